// Round 1
// baseline (440.229 us; speedup 1.0000x reference)
//
#include <hip/hip_runtime.h>
#include <stdint.h>

typedef __attribute__((ext_vector_type(4))) float  f32x4;
typedef __attribute__((ext_vector_type(8))) short  s16x8;
typedef __attribute__((ext_vector_type(4))) short  s16x4;

constexpr int kDIM = 1024;
constexpr int kD   = 64;
constexpr int kNX  = 2048;
constexpr int kNT  = 2304;   // Nx + Nc

static __device__ __forceinline__ float bf2f(short u) {
  union { float f; uint32_t i; } x; x.i = ((uint32_t)(uint16_t)u) << 16; return x.f;
}
static __device__ __forceinline__ short f2bf(float f) {
  union { float f; uint32_t i; } x; x.f = f;
  uint32_t r = x.i + 0x7fffu + ((x.i >> 16) & 1u);
  return (short)(r >> 16);
}

// ---------- cast f32 -> bf16 (n multiple of 1024) ----------
__global__ __launch_bounds__(256) void k_cast(const float* __restrict__ in,
                                              short* __restrict__ out) {
  int i = (blockIdx.x * 256 + threadIdx.x) * 4;
  f32x4 v = *(const f32x4*)(in + i);
  s16x4 o; o[0] = f2bf(v[0]); o[1] = f2bf(v[1]); o[2] = f2bf(v[2]); o[3] = f2bf(v[3]);
  *(s16x4*)(out + i) = o;
}

// ---------- transpose+cast: W[K][N] f32 -> Wt[N][K] bf16 ----------
__global__ __launch_bounds__(256) void k_tcast(const float* __restrict__ W,
                                               short* __restrict__ Wt, int K, int N) {
  __shared__ float tile[32][33];
  int n0 = blockIdx.x * 32, k0 = blockIdx.y * 32;
  int tx = threadIdx.x, ty = threadIdx.y;
#pragma unroll
  for (int i2 = 0; i2 < 4; ++i2) {
    int r = ty + 8 * i2;
    tile[r][tx] = W[(size_t)(k0 + r) * N + n0 + tx];
  }
  __syncthreads();
#pragma unroll
  for (int i2 = 0; i2 < 4; ++i2) {
    int r = ty + 8 * i2;
    Wt[(size_t)(n0 + r) * K + k0 + tx] = f2bf(tile[tx][r]);
  }
}

// ---------- GEMM: C[M][N] = A[M][1024] * Wt[N][1024]^T + bias ----------
// epi==0: N=3072, write q/k (bf16 [BH][pos][64]) and v transposed ([BH][64][pos])
// epi==1: N=1024, write f32 rows to outp
// logical row i -> A row: (i>>rpbs)*arstride + aoff + (i & (rpb-1)); pos = (i&(rpb-1)) + posoff
__global__ __launch_bounds__(256) void k_gemm(
    const short* __restrict__ A, const short* __restrict__ Wt,
    const float* __restrict__ bias,
    short* __restrict__ outq, short* __restrict__ outk, short* __restrict__ outvt,
    float* __restrict__ outp,
    int rpbs, int arstride, int aoff, int posoff, int epi) {
  __shared__ __align__(16) short As[128 * 64];
  __shared__ __align__(16) short Bs[128 * 64];
  const int t = threadIdx.x;
  const int lane = t & 63, w = t >> 6;
  const int g = lane >> 4, r15 = lane & 15;
  const int m0 = blockIdx.y * 128, n0 = blockIdx.x * 128;
  const int wm = w >> 1, wn = w & 1;

  const short* aptr[4]; const short* bptr[4]; int ldso[4];
#pragma unroll
  for (int it = 0; it < 4; ++it) {
    int idx = t + 256 * it;
    int r = idx >> 3, cc = idx & 7;
    int i = m0 + r;
    int arow = (i >> rpbs) * arstride + aoff + (i & ((1 << rpbs) - 1));
    aptr[it] = A + (size_t)arow * kDIM + 8 * cc;
    bptr[it] = Wt + (size_t)(n0 + r) * kDIM + 8 * cc;
    ldso[it] = r * 64 + ((cc ^ (r & 7)) * 8);
  }

  f32x4 acc[4][4] = {};

  for (int kt = 0; kt < 16; ++kt) {
#pragma unroll
    for (int it = 0; it < 4; ++it) {
      *(s16x8*)(As + ldso[it]) = *(const s16x8*)aptr[it];
      *(s16x8*)(Bs + ldso[it]) = *(const s16x8*)bptr[it];
      aptr[it] += 64; bptr[it] += 64;
    }
    __syncthreads();
#pragma unroll
    for (int ks = 0; ks < 2; ++ks) {
      s16x8 af[4], bfr[4];
#pragma unroll
      for (int mf = 0; mf < 4; ++mf) {
        int row = wm * 64 + mf * 16 + r15;
        af[mf] = *(const s16x8*)(As + row * 64 + (((g + 4 * ks) ^ (row & 7)) * 8));
      }
#pragma unroll
      for (int nf = 0; nf < 4; ++nf) {
        int row = wn * 64 + nf * 16 + r15;
        bfr[nf] = *(const s16x8*)(Bs + row * 64 + (((g + 4 * ks) ^ (row & 7)) * 8));
      }
#pragma unroll
      for (int mf = 0; mf < 4; ++mf)
#pragma unroll
        for (int nf = 0; nf < 4; ++nf)
          acc[mf][nf] = __builtin_amdgcn_mfma_f32_16x16x32_bf16(af[mf], bfr[nf], acc[mf][nf], 0, 0, 0);
    }
    __syncthreads();
  }

  const int rpbm = (1 << rpbs) - 1;
#pragma unroll
  for (int mf = 0; mf < 4; ++mf) {
#pragma unroll
    for (int nf = 0; nf < 4; ++nf) {
      int i = m0 + wm * 64 + mf * 16 + 4 * g;   // rows i..i+3 (4-aligned, same batch)
      int j = n0 + wn * 64 + nf * 16 + r15;
      f32x4 v = acc[mf][nf];
      float bj = bias[j];
      v[0] += bj; v[1] += bj; v[2] += bj; v[3] += bj;
      if (epi == 1) {
#pragma unroll
        for (int rg = 0; rg < 4; ++rg)
          outp[(size_t)(i + rg) * 1024 + j] = v[rg];
      } else {
        int e = j >> 10, h = (j >> 6) & 15, d = j & 63;
        int b = i >> rpbs;
        int pos = (i & rpbm) + posoff;
        if (e == 2) {
          size_t base = ((size_t)((b * 16 + h) * 64 + d)) * kNT + pos;
          s16x4 o; o[0] = f2bf(v[0]); o[1] = f2bf(v[1]); o[2] = f2bf(v[2]); o[3] = f2bf(v[3]);
          *(s16x4*)(outvt + base) = o;
        } else {
          short* dst = (e == 0) ? outq : outk;
          size_t base = ((size_t)((b * 16 + h) * kNT + pos)) * 64 + d;
#pragma unroll
          for (int rg = 0; rg < 4; ++rg)
            dst[base + (size_t)rg * 64] = f2bf(v[rg]);
        }
      }
    }
  }
}

// ---------- RMSNorm over head_dim=64, in-place, wave per row ----------
__global__ __launch_bounds__(256) void k_rms(short* __restrict__ X,
                                             const float* __restrict__ sx,
                                             const float* __restrict__ sc) {
  int w = threadIdx.x >> 6, lane = threadIdx.x & 63;
  int pos = blockIdx.x * 4 + w;
  size_t base = ((size_t)blockIdx.y * kNT + pos) * kD;
  float v = bf2f(X[base + lane]);
  float ss = v * v;
  ss += __shfl_xor(ss, 1);  ss += __shfl_xor(ss, 2);  ss += __shfl_xor(ss, 4);
  ss += __shfl_xor(ss, 8);  ss += __shfl_xor(ss, 16); ss += __shfl_xor(ss, 32);
  float r = rsqrtf(ss * (1.f / 64.f) + 1e-6f);
  const float* s = (pos < kNX) ? sx : sc;
  X[base + lane] = f2bf(v * r * s[lane]);
}

// ---------- Flash attention: 16 q-rows/block, 4 waves split KV axis ----------
// S^T = K*Q^T (per-q state lane-local), O^T = V^T*P^T (P stays in registers).
__global__ __launch_bounds__(256) void k_attn(
    const short* __restrict__ Q, const short* __restrict__ K,
    const short* __restrict__ Vt, short* __restrict__ Ao) {
  __shared__ __align__(16) short stage[4][4096];  // per wave: [0,2048)=K tile, [2048,4096)=V^T tile
  __shared__ float Ml[4][2][16];
  const int t = threadIdx.x;
  const int lane = t & 63, w = t >> 6;
  const int g = lane >> 4, r15 = lane & 15;
  const int bh = blockIdx.y;
  const int q0 = blockIdx.x * 16;
  short* Ksw = &stage[w][0];
  short* Vsw = &stage[w][2048];
  const float csc = 0.125f * 1.44269504f;  // log2(e)/8

  // Q B-fragments: n = q = lane&15, k = d = 8g+j (+32*ks)
  const short* qrow = Q + ((size_t)bh * kNT + q0 + r15) * kD;
  s16x8 qf0 = *(const s16x8*)(qrow + 8 * g);
  s16x8 qf1 = *(const s16x8*)(qrow + 32 + 8 * g);

  const short* kptr[4]; const short* vptr[4];
  int kldo[4], vldo0[4], vldo1[4];
#pragma unroll
  for (int it = 0; it < 4; ++it) {
    int idx = lane + 64 * it;
    int r = idx >> 3, cc = idx & 7;
    kptr[it] = K + ((size_t)bh * kNT + r) * kD + 8 * cc + (size_t)w * 32 * kD;
    kldo[it] = r * 64 + ((cc ^ (r & 7)) * 8);
    int d = idx >> 2, c2 = idx & 3;
    vptr[it] = Vt + ((size_t)bh * kD + d) * kNT + 8 * c2 + w * 32;
    int sw = d & 7;
    vldo0[it] = d * 32 + (((2 * c2) ^ sw) * 4);
    vldo1[it] = d * 32 + (((2 * c2 + 1) ^ sw) * 4);
  }

  f32x4 ot[4] = {};
  float m = -1e30f, l = 0.f;

  for (int kt = w; kt < 72; kt += 4) {
#pragma unroll
    for (int it = 0; it < 4; ++it) {
      s16x8 kv8 = *(const s16x8*)kptr[it]; kptr[it] += 4 * 32 * kD;
      *(s16x8*)(Ksw + kldo[it]) = kv8;
      s16x8 vv8 = *(const s16x8*)vptr[it]; vptr[it] += 4 * 32;
      *(s16x4*)(Vsw + vldo0[it]) = __builtin_shufflevector(vv8, vv8, 0, 1, 2, 3);
      *(s16x4*)(Vsw + vldo1[it]) = __builtin_shufflevector(vv8, vv8, 4, 5, 6, 7);
    }
    // S^T = K * Q^T : rows kv (2 frags), col q = lane&15
    f32x4 st0 = {}, st1 = {};
#pragma unroll
    for (int ks = 0; ks < 2; ++ks) {
      s16x8 qk = ks ? qf1 : qf0;
      {
        int row = r15;
        s16x8 kf = *(const s16x8*)(Ksw + row * 64 + (((g + 4 * ks) ^ (row & 7)) * 8));
        st0 = __builtin_amdgcn_mfma_f32_16x16x32_bf16(kf, qk, st0, 0, 0, 0);
      }
      {
        int row = 16 + r15;
        s16x8 kf = *(const s16x8*)(Ksw + row * 64 + (((g + 4 * ks) ^ (row & 7)) * 8));
        st1 = __builtin_amdgcn_mfma_f32_16x16x32_bf16(kf, qk, st1, 0, 0, 0);
      }
    }
    // online softmax (reduction over kv: 8 local values + 2 shuffles)
    float pm = fmaxf(fmaxf(fmaxf(st0[0], st0[1]), fmaxf(st0[2], st0[3])),
                     fmaxf(fmaxf(st1[0], st1[1]), fmaxf(st1[2], st1[3])));
    pm = fmaxf(pm, __shfl_xor(pm, 16));
    pm = fmaxf(pm, __shfl_xor(pm, 32));
    float mn = fmaxf(m, pm);
    float alpha = exp2f((m - mn) * csc);
    float p0[4], p1[4], rs = 0.f;
#pragma unroll
    for (int r2 = 0; r2 < 4; ++r2) {
      p0[r2] = exp2f((st0[r2] - mn) * csc);
      p1[r2] = exp2f((st1[r2] - mn) * csc);
      rs += p0[r2] + p1[r2];
    }
    rs += __shfl_xor(rs, 16);
    rs += __shfl_xor(rs, 32);
    l = l * alpha + rs;
    m = mn;
#pragma unroll
    for (int mf = 0; mf < 4; ++mf) {
      ot[mf][0] *= alpha; ot[mf][1] *= alpha; ot[mf][2] *= alpha; ot[mf][3] *= alpha;
    }
    // P^T pack: element j <-> kv = 4g + (j&3) + 16*(j>>2)  (natural C-layout order)
    s16x8 pf;
    pf[0] = f2bf(p0[0]); pf[1] = f2bf(p0[1]); pf[2] = f2bf(p0[2]); pf[3] = f2bf(p0[3]);
    pf[4] = f2bf(p1[0]); pf[5] = f2bf(p1[1]); pf[6] = f2bf(p1[2]); pf[7] = f2bf(p1[3]);
    // O^T += V^T * P^T : A elem j = V^T[d][4g+(j&3)+16*(j>>2)]  (two b64 slots)
#pragma unroll
    for (int mf = 0; mf < 4; ++mf) {
      int d = mf * 16 + r15;
      int sw = d & 7;
      s16x4 vlo = *(const s16x4*)(Vsw + d * 32 + ((g ^ sw) * 4));
      s16x4 vhi = *(const s16x4*)(Vsw + d * 32 + (((4 + g) ^ sw) * 4));
      s16x8 vf = __builtin_shufflevector(vlo, vhi, 0, 1, 2, 3, 4, 5, 6, 7);
      ot[mf] = __builtin_amdgcn_mfma_f32_16x16x32_bf16(vf, pf, ot[mf], 0, 0, 0);
    }
  }

  __syncthreads();
  // merge 4 waves' partial (O^T, m, l) via LDS (aliases staging area)
  float* Om = (float*)&stage[0][0];  // [4][64][17] f32, padded stride
#pragma unroll
  for (int mf = 0; mf < 4; ++mf)
#pragma unroll
    for (int rg = 0; rg < 4; ++rg) {
      int d = mf * 16 + 4 * g + rg;
      Om[(w * 64 + d) * 17 + r15] = ot[mf][rg];
    }
  if (g == 0) { Ml[w][0][r15] = m; Ml[w][1][r15] = l; }
  __syncthreads();
#pragma unroll
  for (int rep = 0; rep < 4; ++rep) {
    int idx = t + 256 * rep;
    int d = idx & 63, q = idx >> 6;
    float m0v = Ml[0][0][q], m1v = Ml[1][0][q], m2v = Ml[2][0][q], m3v = Ml[3][0][q];
    float mm = fmaxf(fmaxf(m0v, m1v), fmaxf(m2v, m3v));
    float a0 = exp2f((m0v - mm) * csc), a1 = exp2f((m1v - mm) * csc);
    float a2 = exp2f((m2v - mm) * csc), a3 = exp2f((m3v - mm) * csc);
    float ll = Ml[0][1][q] * a0 + Ml[1][1][q] * a1 + Ml[2][1][q] * a2 + Ml[3][1][q] * a3;
    float val = Om[(0 * 64 + d) * 17 + q] * a0 + Om[(1 * 64 + d) * 17 + q] * a1 +
                Om[(2 * 64 + d) * 17 + q] * a2 + Om[(3 * 64 + d) * 17 + q] * a3;
    val /= ll;
    int b = bh >> 4, h = bh & 15;
    Ao[((size_t)b * kNT + q0 + q) * kDIM + h * kD + d] = f2bf(val);
  }
}

extern "C" void kernel_launch(void* const* d_in, const int* in_sizes, int n_in,
                              void* d_out, int out_size, void* d_ws, size_t ws_size,
                              hipStream_t stream) {
  const float* x   = (const float*)d_in[0];
  const float* c   = (const float*)d_in[1];
  const float* wqx = (const float*)d_in[2];
  const float* bqx = (const float*)d_in[3];
  const float* wqc = (const float*)d_in[4];
  const float* bqc = (const float*)d_in[5];
  const float* sqx = (const float*)d_in[6];
  const float* skx = (const float*)d_in[7];
  const float* sqc = (const float*)d_in[8];
  const float* skc = (const float*)d_in[9];
  const float* wpx = (const float*)d_in[10];
  const float* bpx = (const float*)d_in[11];
  const float* wpc = (const float*)d_in[12];
  const float* bpc = (const float*)d_in[13];
  float* out = (float*)d_out;

  char* p = (char*)d_ws;
  short* xb   = (short*)p; p += (size_t)4096 * 1024 * 2;
  short* cb   = (short*)p; p += (size_t)512 * 1024 * 2;
  short* wqxt = (short*)p; p += (size_t)3072 * 1024 * 2;
  short* wqct = (short*)p; p += (size_t)3072 * 1024 * 2;
  short* wpxt = (short*)p; p += (size_t)1024 * 1024 * 2;
  short* wpct = (short*)p; p += (size_t)1024 * 1024 * 2;
  short* qb   = (short*)p; p += (size_t)32 * 2304 * 64 * 2;
  short* kb   = (short*)p; p += (size_t)32 * 2304 * 64 * 2;
  short* vtb  = (short*)p; p += (size_t)32 * 64 * 2304 * 2;
  short* ao   = (short*)p; p += (size_t)2 * 2304 * 1024 * 2;

  k_cast<<<4096, 256, 0, stream>>>(x, xb);
  k_cast<<<512, 256, 0, stream>>>(c, cb);
  k_tcast<<<dim3(96, 32), dim3(32, 8), 0, stream>>>(wqx, wqxt, 1024, 3072);
  k_tcast<<<dim3(96, 32), dim3(32, 8), 0, stream>>>(wqc, wqct, 1024, 3072);
  k_tcast<<<dim3(32, 32), dim3(32, 8), 0, stream>>>(wpx, wpxt, 1024, 1024);
  k_tcast<<<dim3(32, 32), dim3(32, 8), 0, stream>>>(wpc, wpct, 1024, 1024);

  // QKV projections (+bias), q/k -> [BH][pos][64], v -> [BH][64][pos]
  k_gemm<<<dim3(24, 32), 256, 0, stream>>>(xb, wqxt, bqx, qb, kb, vtb, nullptr, 11, 2048, 0, 0, 0);
  k_gemm<<<dim3(24, 4),  256, 0, stream>>>(cb, wqct, bqc, qb, kb, vtb, nullptr, 8, 256, 0, 2048, 0);

  k_rms<<<dim3(576, 32), 256, 0, stream>>>(qb, sqx, sqc);
  k_rms<<<dim3(576, 32), 256, 0, stream>>>(kb, skx, skc);

  k_attn<<<dim3(144, 32), 256, 0, stream>>>(qb, kb, vtb, ao);

  // output projections (f32 + bias) straight into d_out
  k_gemm<<<dim3(8, 32), 256, 0, stream>>>(ao, wpxt, bpx, nullptr, nullptr, nullptr, out, 11, 2304, 0, 0, 1);
  k_gemm<<<dim3(8, 4),  256, 0, stream>>>(ao, wpct, bpc, nullptr, nullptr, nullptr,
                                          out + (size_t)4096 * 1024, 8, 2304, 2048, 0, 1);
}

// Round 2
// 253.226 us; speedup vs baseline: 1.7385x; 1.7385x over previous
//
#include <hip/hip_runtime.h>
#include <stdint.h>

typedef __attribute__((ext_vector_type(4))) float  f32x4;
typedef __attribute__((ext_vector_type(8))) short  s16x8;
typedef __attribute__((ext_vector_type(4))) short  s16x4;

constexpr int kDIM = 1024;
constexpr int kD   = 64;
constexpr int kNX  = 2048;
constexpr int kNT  = 2304;   // Nx + Nc

static __device__ __forceinline__ float bf2f(short u) {
  union { float f; uint32_t i; } x; x.i = ((uint32_t)(uint16_t)u) << 16; return x.f;
}
static __device__ __forceinline__ short f2bf(float f) {
  union { float f; uint32_t i; } x; x.f = f;
  uint32_t r = x.i + 0x7fffu + ((x.i >> 16) & 1u);
  return (short)(r >> 16);
}
static __device__ __forceinline__ uint32_t cvtpk(float lo, float hi) {
  uint32_t r;
  asm volatile("v_cvt_pk_bf16_f32 %0, %1, %2" : "=v"(r) : "v"(lo), "v"(hi));
  return r;
}
// async global->LDS, 16B per lane; LDS dest = wave-uniform base + lane*16
static __device__ __forceinline__ void gll16(const short* g, short* l) {
  __builtin_amdgcn_global_load_lds((const __attribute__((address_space(1))) void*)g,
                                   (__attribute__((address_space(3))) void*)l, 16, 0, 0);
}

// ---------- cast f32 -> bf16 (n multiple of 1024) ----------
__global__ __launch_bounds__(256) void k_cast(const float* __restrict__ in,
                                              short* __restrict__ out) {
  int i = (blockIdx.x * 256 + threadIdx.x) * 4;
  f32x4 v = *(const f32x4*)(in + i);
  s16x4 o; o[0] = f2bf(v[0]); o[1] = f2bf(v[1]); o[2] = f2bf(v[2]); o[3] = f2bf(v[3]);
  *(s16x4*)(out + i) = o;
}

// ---------- transpose+cast: W[K][N] f32 -> Wt[N][K] bf16 ----------
__global__ __launch_bounds__(256) void k_tcast(const float* __restrict__ W,
                                               short* __restrict__ Wt, int K, int N) {
  __shared__ float tile[32][33];
  int n0 = blockIdx.x * 32, k0 = blockIdx.y * 32;
  int tx = threadIdx.x, ty = threadIdx.y;
#pragma unroll
  for (int i2 = 0; i2 < 4; ++i2) {
    int r = ty + 8 * i2;
    tile[r][tx] = W[(size_t)(k0 + r) * N + n0 + tx];
  }
  __syncthreads();
#pragma unroll
  for (int i2 = 0; i2 < 4; ++i2) {
    int r = ty + 8 * i2;
    Wt[(size_t)(n0 + r) * K + k0 + tx] = f2bf(tile[tx][r]);
  }
}

// ---------- GEMM: C[M][N] = A[M][1024] * Wt[N][1024]^T + bias ----------
// Staging via global_load_lds w=16, swizzle folded into SOURCE address (LDS linear).
// epi==0: N=3072, write q/k (bf16 [BH][pos][64]) and v transposed+column-permuted
// epi==1: N=1024, write f32 rows to outp
__global__ __launch_bounds__(256) void k_gemm(
    const short* __restrict__ A, const short* __restrict__ Wt,
    const float* __restrict__ bias,
    short* __restrict__ outq, short* __restrict__ outk, short* __restrict__ outvt,
    float* __restrict__ outp,
    int rpbs, int arstride, int aoff, int posoff, int epi) {
  __shared__ __align__(16) short As[128 * 64];
  __shared__ __align__(16) short Bs[128 * 64];
  const int t = threadIdx.x;
  const int lane = t & 63, w = t >> 6;
  const int g = lane >> 4, r15 = lane & 15;
  const int m0 = blockIdx.y * 128, n0 = blockIdx.x * 128;
  const int wm = w >> 1, wn = w & 1;

  const short* aptr[4]; const short* bptr[4];
  short* alds[4]; short* blds[4];
#pragma unroll
  for (int it = 0; it < 4; ++it) {
    int slot = t + 256 * it;
    int row = slot >> 3, gp = slot & 7;
    int gl = gp ^ (row & 7);               // pre-swizzled source group
    int i = m0 + row;
    int arow = (i >> rpbs) * arstride + aoff + (i & ((1 << rpbs) - 1));
    aptr[it] = A + (size_t)arow * kDIM + 8 * gl;
    bptr[it] = Wt + (size_t)(n0 + row) * kDIM + 8 * gl;
    int wbase = (256 * it + 64 * w) * 8;   // wave-uniform LDS slot base (shorts)
    alds[it] = As + wbase;
    blds[it] = Bs + wbase;
  }

  f32x4 acc[4][4] = {};

  for (int kt = 0; kt < 16; ++kt) {
#pragma unroll
    for (int it = 0; it < 4; ++it) {
      gll16(aptr[it], alds[it]);
      gll16(bptr[it], blds[it]);
      aptr[it] += 64; bptr[it] += 64;
    }
    __syncthreads();
#pragma unroll
    for (int ks = 0; ks < 2; ++ks) {
      s16x8 af[4], bfr[4];
#pragma unroll
      for (int mf = 0; mf < 4; ++mf) {
        int row = wm * 64 + mf * 16 + r15;
        af[mf] = *(const s16x8*)(As + row * 64 + (((g + 4 * ks) ^ (row & 7)) * 8));
      }
#pragma unroll
      for (int nf = 0; nf < 4; ++nf) {
        int row = wn * 64 + nf * 16 + r15;
        bfr[nf] = *(const s16x8*)(Bs + row * 64 + (((g + 4 * ks) ^ (row & 7)) * 8));
      }
#pragma unroll
      for (int mf = 0; mf < 4; ++mf)
#pragma unroll
        for (int nf = 0; nf < 4; ++nf)
          acc[mf][nf] = __builtin_amdgcn_mfma_f32_16x16x32_bf16(af[mf], bfr[nf], acc[mf][nf], 0, 0, 0);
    }
    __syncthreads();
  }

  const int rpbm = (1 << rpbs) - 1;
#pragma unroll
  for (int mf = 0; mf < 4; ++mf) {
#pragma unroll
    for (int nf = 0; nf < 4; ++nf) {
      int i = m0 + wm * 64 + mf * 16 + 4 * g;   // rows i..i+3 (4-aligned, same batch)
      int j = n0 + wn * 64 + nf * 16 + r15;
      f32x4 v = acc[mf][nf];
      float bj = bias[j];
      v[0] += bj; v[1] += bj; v[2] += bj; v[3] += bj;
      if (epi == 1) {
#pragma unroll
        for (int rg = 0; rg < 4; ++rg)
          outp[(size_t)(i + rg) * 1024 + j] = v[rg];
      } else {
        int e = j >> 10, h = (j >> 6) & 15, d = j & 63;
        int b = i >> rpbs;
        int pos = (i & rpbm) + posoff;
        if (e == 2) {
          // permuted column order within each 64-block:
          // pos bits [5]=c,[4]=b2,[3:2]=g,[1:0]=r  ->  pg bits [5]=c,[4:3]=g,[2]=b2,[1:0]=r
          int pg = (pos & ~63) | (pos & 32) | (((pos >> 2) & 3) << 3) |
                   (((pos >> 4) & 1) << 2) | (pos & 3);
          size_t base = ((size_t)((b * 16 + h) * 64 + d)) * kNT + pg;
          s16x4 o; o[0] = f2bf(v[0]); o[1] = f2bf(v[1]); o[2] = f2bf(v[2]); o[3] = f2bf(v[3]);
          *(s16x4*)(outvt + base) = o;
        } else {
          short* dst = (e == 0) ? outq : outk;
          size_t base = ((size_t)((b * 16 + h) * kNT + pos)) * 64 + d;
#pragma unroll
          for (int rg = 0; rg < 4; ++rg)
            dst[base + (size_t)rg * 64] = f2bf(v[rg]);
        }
      }
    }
  }
}

// ---------- RMSNorm over head_dim=64, in-place, wave per row ----------
__global__ __launch_bounds__(256) void k_rms(short* __restrict__ X,
                                             const float* __restrict__ sx,
                                             const float* __restrict__ sc) {
  int w = threadIdx.x >> 6, lane = threadIdx.x & 63;
  int pos = blockIdx.x * 4 + w;
  size_t base = ((size_t)blockIdx.y * kNT + pos) * kD;
  float v = bf2f(X[base + lane]);
  float ss = v * v;
  ss += __shfl_xor(ss, 1);  ss += __shfl_xor(ss, 2);  ss += __shfl_xor(ss, 4);
  ss += __shfl_xor(ss, 8);  ss += __shfl_xor(ss, 16); ss += __shfl_xor(ss, 32);
  float r = rsqrtf(ss * (1.f / 64.f) + 1e-6f);
  const float* s = (pos < kNX) ? sx : sc;
  X[base + lane] = f2bf(v * r * s[lane]);
}

// ---------- Flash attention: QBLK=64 (4 waves x 16 q), shared KV, KVBLK=64, dbuf ----------
// S^T = K*Q^T (per-q state lane-local), O^T = V^T*P^T (P stays in registers).
__global__ __launch_bounds__(256) void k_attn(
    const short* __restrict__ Q, const short* __restrict__ K,
    const short* __restrict__ Vt, short* __restrict__ Ao) {
  __shared__ __align__(16) short Ks[2][64 * 64];  // [kv][d], 8-grp src-swizzled
  __shared__ __align__(16) short Vs[2][64 * 64];  // [d][kv'], kv' pre-permuted in global
  const int t = threadIdx.x;
  const int lane = t & 63, w = t >> 6;
  const int g = lane >> 4, r15 = lane & 15;
  const int bh = blockIdx.y;
  const int q0 = blockIdx.x * 64;
  const float csc = 0.125f * 1.44269504f;  // scale * log2(e)

  // Q B-fragments (q = q0 + 16w + r15): element j -> d = 8g + j + 32ks
  const short* qrow = Q + ((size_t)bh * kNT + q0 + 16 * w + r15) * kD;
  s16x8 qf0 = *(const s16x8*)(qrow + 8 * g);
  s16x8 qf1 = *(const s16x8*)(qrow + 32 + 8 * g);

  // staging: 512 slots per matrix per tile, 2 per thread
  const short* kptr[2]; const short* vptr[2];
  short* klds[2]; short* vlds[2];
#pragma unroll
  for (int it = 0; it < 2; ++it) {
    int slot = t + 256 * it;
    int row = slot >> 3, gp = slot & 7;
    int gl = gp ^ (row & 7);
    kptr[it] = K + ((size_t)bh * kNT + row) * kD + 8 * gl;
    vptr[it] = Vt + ((size_t)bh * kD + row) * kNT + 8 * gl;
    int wbase = (256 * it + 64 * w) * 8;
    klds[it] = &Ks[0][0] + wbase;
    vlds[it] = &Vs[0][0] + wbase;
  }

  f32x4 ot[4] = {};
  float m = -1e30f, l = 0.f;
  int cur = 0;

  // prologue: issue tile 0 into buffer 0
#pragma unroll
  for (int it = 0; it < 2; ++it) { gll16(kptr[it], klds[it]); gll16(vptr[it], vlds[it]); }

  for (int kt = 0; kt < 36; ++kt) {
    __syncthreads();  // drains this wave's gll (vmcnt) + everyone's reads of buf cur^1
    if (kt != 35) {
#pragma unroll
      for (int it = 0; it < 2; ++it) {
        kptr[it] += 64 * kD; vptr[it] += 64;
        gll16(kptr[it], klds[it] + (cur ^ 1) * 4096);
        gll16(vptr[it], vlds[it] + (cur ^ 1) * 4096);
      }
    }
    const short* Kb = &Ks[cur][0];
    const short* Vb = &Vs[cur][0];

    // S^T = K * Q^T : rows kv = 16rf + r15, col q = r15 (as C-col)
    f32x4 st[4] = {};
#pragma unroll
    for (int ks = 0; ks < 2; ++ks) {
      s16x8 qk = ks ? qf1 : qf0;
#pragma unroll
      for (int rf = 0; rf < 4; ++rf) {
        int row = 16 * rf + r15;
        s16x8 kf = *(const s16x8*)(Kb + row * 64 + (((g + 4 * ks) ^ (row & 7)) * 8));
        st[rf] = __builtin_amdgcn_mfma_f32_16x16x32_bf16(kf, qk, st[rf], 0, 0, 0);
      }
    }

    // online softmax: 16 local scores + cross-g combine (2 shuffles each)
    float pm = st[0][0];
#pragma unroll
    for (int rf = 0; rf < 4; ++rf)
#pragma unroll
      for (int j = 0; j < 4; ++j) pm = fmaxf(pm, st[rf][j]);
    pm = fmaxf(pm, __shfl_xor(pm, 16));
    pm = fmaxf(pm, __shfl_xor(pm, 32));
    bool skip = (__ballot(pm - m <= 16.0f) == ~0ull);  // defer-max: p bounded by 2^2.9
    float mn = skip ? m : fmaxf(m, pm);
    float p[4][4]; float rs = 0.f;
#pragma unroll
    for (int rf = 0; rf < 4; ++rf)
#pragma unroll
      for (int j = 0; j < 4; ++j) {
        p[rf][j] = exp2f((st[rf][j] - mn) * csc);
        rs += p[rf][j];
      }
    rs += __shfl_xor(rs, 16);
    rs += __shfl_xor(rs, 32);
    if (!skip) {
      float alpha = exp2f((m - mn) * csc);
      l *= alpha;
#pragma unroll
      for (int mf = 0; mf < 4; ++mf) {
        ot[mf][0] *= alpha; ot[mf][1] *= alpha; ot[mf][2] *= alpha; ot[mf][3] *= alpha;
      }
      m = mn;
    }
    l += rs;

    // P^T pack: element j <-> kv = 32c + 4g + (j&3) + 16*(j>>2)
    s16x8 pf[2];
#pragma unroll
    for (int c = 0; c < 2; ++c) {
      union { uint32_t u[4]; s16x8 v; } pk;
      pk.u[0] = cvtpk(p[2 * c][0], p[2 * c][1]);
      pk.u[1] = cvtpk(p[2 * c][2], p[2 * c][3]);
      pk.u[2] = cvtpk(p[2 * c + 1][0], p[2 * c + 1][1]);
      pk.u[3] = cvtpk(p[2 * c + 1][2], p[2 * c + 1][3]);
      pf[c] = pk.v;
    }

    // O^T += V^T * P^T : A elem j = Vs[d][kv' = 32c + 8g + j] (contiguous b128)
#pragma unroll
    for (int mf = 0; mf < 4; ++mf) {
      int d = 16 * mf + r15;
#pragma unroll
      for (int c = 0; c < 2; ++c) {
        s16x8 vf = *(const s16x8*)(Vb + d * 64 + (((4 * c + g) ^ (d & 7)) * 8));
        ot[mf] = __builtin_amdgcn_mfma_f32_16x16x32_bf16(vf, pf[c], ot[mf], 0, 0, 0);
      }
    }
    cur ^= 1;
  }

  // epilogue: transpose O^T -> O via LDS (reuse Ks as f32), coalesced bf16 store
  __syncthreads();
  float* Os = (float*)&Ks[0][0];  // 4096 floats, [wave][16 q][64 d] XOR-swizzled
  float rl = 1.f / l;
#pragma unroll
  for (int mf = 0; mf < 4; ++mf)
#pragma unroll
    for (int rg = 0; rg < 4; ++rg) {
      int d = 16 * mf + 4 * g + rg;
      Os[w * 1024 + r15 * 64 + (d ^ ((r15 & 7) << 3))] = ot[mf][rg] * rl;
    }
  __syncthreads();
  {
    int w2 = t >> 6, ql = (t & 63) >> 2, c4 = t & 3;
    int b = bh >> 4, h = bh & 15;
    float vals[16];
#pragma unroll
    for (int i = 0; i < 4; ++i) {
      f32x4 rd = *(const f32x4*)&Os[w2 * 1024 + ql * 64 + (((c4 * 16 + 4 * i) ^ ((ql & 7) << 3)))];
      vals[4 * i + 0] = rd[0]; vals[4 * i + 1] = rd[1];
      vals[4 * i + 2] = rd[2]; vals[4 * i + 3] = rd[3];
    }
    union { uint32_t u[4]; s16x8 v; } o0, o1;
    o0.u[0] = cvtpk(vals[0], vals[1]);   o0.u[1] = cvtpk(vals[2], vals[3]);
    o0.u[2] = cvtpk(vals[4], vals[5]);   o0.u[3] = cvtpk(vals[6], vals[7]);
    o1.u[0] = cvtpk(vals[8], vals[9]);   o1.u[1] = cvtpk(vals[10], vals[11]);
    o1.u[2] = cvtpk(vals[12], vals[13]); o1.u[3] = cvtpk(vals[14], vals[15]);
    short* dst = Ao + ((size_t)b * kNT + q0 + 16 * w2 + ql) * kDIM + h * kD + c4 * 16;
    *(s16x8*)dst = o0.v;
    *(s16x8*)(dst + 8) = o1.v;
  }
}

extern "C" void kernel_launch(void* const* d_in, const int* in_sizes, int n_in,
                              void* d_out, int out_size, void* d_ws, size_t ws_size,
                              hipStream_t stream) {
  const float* x   = (const float*)d_in[0];
  const float* c   = (const float*)d_in[1];
  const float* wqx = (const float*)d_in[2];
  const float* bqx = (const float*)d_in[3];
  const float* wqc = (const float*)d_in[4];
  const float* bqc = (const float*)d_in[5];
  const float* sqx = (const float*)d_in[6];
  const float* skx = (const float*)d_in[7];
  const float* sqc = (const float*)d_in[8];
  const float* skc = (const float*)d_in[9];
  const float* wpx = (const float*)d_in[10];
  const float* bpx = (const float*)d_in[11];
  const float* wpc = (const float*)d_in[12];
  const float* bpc = (const float*)d_in[13];
  float* out = (float*)d_out;

  char* p = (char*)d_ws;
  short* xb   = (short*)p; p += (size_t)4096 * 1024 * 2;
  short* cb   = (short*)p; p += (size_t)512 * 1024 * 2;
  short* wqxt = (short*)p; p += (size_t)3072 * 1024 * 2;
  short* wqct = (short*)p; p += (size_t)3072 * 1024 * 2;
  short* wpxt = (short*)p; p += (size_t)1024 * 1024 * 2;
  short* wpct = (short*)p; p += (size_t)1024 * 1024 * 2;
  short* qb   = (short*)p; p += (size_t)32 * 2304 * 64 * 2;
  short* kb   = (short*)p; p += (size_t)32 * 2304 * 64 * 2;
  short* vtb  = (short*)p; p += (size_t)32 * 64 * 2304 * 2;
  short* ao   = (short*)p; p += (size_t)2 * 2304 * 1024 * 2;

  k_cast<<<4096, 256, 0, stream>>>(x, xb);
  k_cast<<<512, 256, 0, stream>>>(c, cb);
  k_tcast<<<dim3(96, 32), dim3(32, 8), 0, stream>>>(wqx, wqxt, 1024, 3072);
  k_tcast<<<dim3(96, 32), dim3(32, 8), 0, stream>>>(wqc, wqct, 1024, 3072);
  k_tcast<<<dim3(32, 32), dim3(32, 8), 0, stream>>>(wpx, wpxt, 1024, 1024);
  k_tcast<<<dim3(32, 32), dim3(32, 8), 0, stream>>>(wpc, wpct, 1024, 1024);

  // QKV projections (+bias), q/k -> [BH][pos][64], v -> [BH][64][pos] (col-permuted)
  k_gemm<<<dim3(24, 32), 256, 0, stream>>>(xb, wqxt, bqx, qb, kb, vtb, nullptr, 11, 2048, 0, 0, 0);
  k_gemm<<<dim3(24, 4),  256, 0, stream>>>(cb, wqct, bqc, qb, kb, vtb, nullptr, 8, 256, 0, 2048, 0);

  k_rms<<<dim3(576, 32), 256, 0, stream>>>(qb, sqx, sqc);
  k_rms<<<dim3(576, 32), 256, 0, stream>>>(kb, skx, skc);

  k_attn<<<dim3(36, 32), 256, 0, stream>>>(qb, kb, vtb, ao);

  // output projections (f32 + bias) straight into d_out
  k_gemm<<<dim3(8, 32), 256, 0, stream>>>(ao, wpxt, bpx, nullptr, nullptr, nullptr, out, 11, 2304, 0, 0, 1);
  k_gemm<<<dim3(8, 4),  256, 0, stream>>>(ao, wpct, bpc, nullptr, nullptr, nullptr,
                                          out + (size_t)4096 * 1024, 8, 2304, 2048, 0, 1);
}

// Round 3
// 218.886 us; speedup vs baseline: 2.0112x; 1.1569x over previous
//
#include <hip/hip_runtime.h>
#include <stdint.h>

typedef __attribute__((ext_vector_type(4))) float  f32x4;
typedef __attribute__((ext_vector_type(8))) short  s16x8;
typedef __attribute__((ext_vector_type(4))) short  s16x4;

constexpr int kDIM = 1024;
constexpr int kD   = 64;
constexpr int kNT  = 2304;   // Nx + Nc

static __device__ __forceinline__ float bf2f(short u) {
  union { float f; uint32_t i; } x; x.i = ((uint32_t)(uint16_t)u) << 16; return x.f;
}
static __device__ __forceinline__ short f2bf(float f) {
  union { float f; uint32_t i; } x; x.f = f;
  uint32_t r = x.i + 0x7fffu + ((x.i >> 16) & 1u);
  return (short)(r >> 16);
}
static __device__ __forceinline__ uint32_t cvtpk(float lo, float hi) {
  uint32_t r;
  asm volatile("v_cvt_pk_bf16_f32 %0, %1, %2" : "=v"(r) : "v"(lo), "v"(hi));
  return r;
}
// async global->LDS, 16B per lane; LDS dest = wave-uniform base + lane*16
static __device__ __forceinline__ void gll16(const short* g, short* l) {
  __builtin_amdgcn_global_load_lds((const __attribute__((address_space(1))) void*)g,
                                   (__attribute__((address_space(3))) void*)l, 16, 0, 0);
}

// ---------- cast f32 -> bf16 (x and c in one launch) ----------
__global__ __launch_bounds__(256) void k_cast2(const float* __restrict__ x,
                                               short* __restrict__ xb,
                                               const float* __restrict__ c,
                                               short* __restrict__ cb, int nxb) {
  int b = blockIdx.x;
  const float* in = x; short* out = xb;
  if (b >= nxb) { in = c; out = cb; b -= nxb; }
  int i = (b * 256 + threadIdx.x) * 4;
  f32x4 v = *(const f32x4*)(in + i);
  s16x4 o; o[0] = f2bf(v[0]); o[1] = f2bf(v[1]); o[2] = f2bf(v[2]); o[3] = f2bf(v[3]);
  *(s16x4*)(out + i) = o;
}

// ---------- transpose+cast: W[K][N] f32 -> Wt[N][K] bf16, two weights per launch ----------
__global__ __launch_bounds__(256) void k_tcast2(const float* __restrict__ W0,
                                                short* __restrict__ Wt0,
                                                const float* __restrict__ W1,
                                                short* __restrict__ Wt1,
                                                int K, int N) {
  const float* W = blockIdx.z ? W1 : W0;
  short* Wt = blockIdx.z ? Wt1 : Wt0;
  __shared__ float tile[32][33];
  int n0 = blockIdx.x * 32, k0 = blockIdx.y * 32;
  int tx = threadIdx.x, ty = threadIdx.y;
#pragma unroll
  for (int i2 = 0; i2 < 4; ++i2) {
    int r = ty + 8 * i2;
    tile[r][tx] = W[(size_t)(k0 + r) * N + n0 + tx];
  }
  __syncthreads();
#pragma unroll
  for (int i2 = 0; i2 < 4; ++i2) {
    int r = ty + 8 * i2;
    Wt[(size_t)(n0 + r) * K + k0 + tx] = f2bf(tile[tx][r]);
  }
}

// ---------- GEMM: C = A * Wt^T + bias, two param-sets per launch (grid.y split) ----------
// epi==0: N=3072, fused RMSNorm on q/k heads, v transposed+col-permuted
// epi==1: N=1024, f32 rows to outp
__global__ __launch_bounds__(256) void k_gemm(
    const short* A0, const short* Wt0, const float* bias0,
    const float* sq0, const float* sk0,
    const short* A1, const short* Wt1, const float* bias1,
    const float* sq1, const float* sk1,
    short* outq, short* outk, short* outvt,
    float* outp0, float* outp1,
    int rpbs0, int arstride0, int aoff0, int posoff0,
    int rpbs1, int arstride1, int aoff1, int posoff1,
    int ybreak, int epi) {
  __shared__ __align__(16) short As[128 * 64];
  __shared__ __align__(16) short Bs[128 * 64];
  const int t = threadIdx.x;
  const int lane = t & 63, w = t >> 6;
  const int g = lane >> 4, r15 = lane & 15;
  const int wm = w >> 1, wn = w & 1;

  int by = blockIdx.y;
  const short* A; const short* Wt; const float* bias;
  const float* sq; const float* sk; float* outp;
  int rpbs, arstride, aoff, posoff, my;
  if (by < ybreak) {
    A = A0; Wt = Wt0; bias = bias0; sq = sq0; sk = sk0; outp = outp0;
    rpbs = rpbs0; arstride = arstride0; aoff = aoff0; posoff = posoff0; my = by;
  } else {
    A = A1; Wt = Wt1; bias = bias1; sq = sq1; sk = sk1; outp = outp1;
    rpbs = rpbs1; arstride = arstride1; aoff = aoff1; posoff = posoff1; my = by - ybreak;
  }
  const int m0 = my * 128, n0 = blockIdx.x * 128;

  const short* aptr[4]; const short* bptr[4];
  short* alds[4]; short* blds[4];
#pragma unroll
  for (int it = 0; it < 4; ++it) {
    int slot = t + 256 * it;
    int row = slot >> 3, gp = slot & 7;
    int gl = gp ^ (row & 7);               // pre-swizzled source group
    int i = m0 + row;
    int arow = (i >> rpbs) * arstride + aoff + (i & ((1 << rpbs) - 1));
    aptr[it] = A + (size_t)arow * kDIM + 8 * gl;
    bptr[it] = Wt + (size_t)(n0 + row) * kDIM + 8 * gl;
    int wbase = (256 * it + 64 * w) * 8;   // wave-uniform LDS slot base (shorts)
    alds[it] = As + wbase;
    blds[it] = Bs + wbase;
  }

  f32x4 acc[4][4] = {};

  for (int kt = 0; kt < 16; ++kt) {
#pragma unroll
    for (int it = 0; it < 4; ++it) {
      gll16(aptr[it], alds[it]);
      gll16(bptr[it], blds[it]);
      aptr[it] += 64; bptr[it] += 64;
    }
    __syncthreads();
#pragma unroll
    for (int ks = 0; ks < 2; ++ks) {
      s16x8 af[4], bfr[4];
#pragma unroll
      for (int mf = 0; mf < 4; ++mf) {
        int row = wm * 64 + mf * 16 + r15;
        af[mf] = *(const s16x8*)(As + row * 64 + (((g + 4 * ks) ^ (row & 7)) * 8));
      }
#pragma unroll
      for (int nf = 0; nf < 4; ++nf) {
        int row = wn * 64 + nf * 16 + r15;
        bfr[nf] = *(const s16x8*)(Bs + row * 64 + (((g + 4 * ks) ^ (row & 7)) * 8));
      }
#pragma unroll
      for (int mf = 0; mf < 4; ++mf)
#pragma unroll
        for (int nf = 0; nf < 4; ++nf)
          acc[mf][nf] = __builtin_amdgcn_mfma_f32_16x16x32_bf16(af[mf], bfr[nf], acc[mf][nf], 0, 0, 0);
    }
    __syncthreads();
  }

  const int rpbm = (1 << rpbs) - 1;
  if (epi == 1) {
#pragma unroll
    for (int mf = 0; mf < 4; ++mf)
#pragma unroll
      for (int nf = 0; nf < 4; ++nf) {
        int i = m0 + wm * 64 + mf * 16 + 4 * g;
        int j = n0 + wn * 64 + nf * 16 + r15;
        f32x4 v = acc[mf][nf];
        float bj = bias[j];
#pragma unroll
        for (int rg = 0; rg < 4; ++rg) {
          int ii = i + rg;
          int arow = (ii >> rpbs) * 0;  // rows map 1:1 to output rows here
          (void)arow;
          outp[(size_t)ii * 1024 + j] = v[rg] + bj;
        }
      }
    return;
  }
  const int eblk = (n0 + wn * 64) >> 10;   // wave-uniform: 0=q, 1=k, 2=v
  const int hh = ((n0 + wn * 64) >> 6) & 15;
  if (eblk == 2) {
#pragma unroll
    for (int mf = 0; mf < 4; ++mf)
#pragma unroll
      for (int nf = 0; nf < 4; ++nf) {
        int i = m0 + wm * 64 + mf * 16 + 4 * g;
        int j = n0 + wn * 64 + nf * 16 + r15;
        f32x4 v = acc[mf][nf];
        float bj = bias[j];
        int d = j & 63;
        int b = i >> rpbs;
        int pos = (i & rpbm) + posoff;
        // permuted column order within each 64-block (keeps low 2 bits):
        int pg = (pos & ~63) | (pos & 32) | (((pos >> 2) & 3) << 3) |
                 (((pos >> 4) & 1) << 2) | (pos & 3);
        size_t base = ((size_t)((b * 16 + hh) * 64 + d)) * kNT + pg;
        s16x4 o;
        o[0] = f2bf(v[0] + bj); o[1] = f2bf(v[1] + bj);
        o[2] = f2bf(v[2] + bj); o[3] = f2bf(v[3] + bj);
        *(s16x4*)(outvt + base) = o;
      }
  } else {
    const float* sv = (eblk == 0) ? sq : sk;
    short* dstb = (eblk == 0) ? outq : outk;
    float sl[4], bj4[4];
#pragma unroll
    for (int nf = 0; nf < 4; ++nf) {
      bj4[nf] = bias[n0 + wn * 64 + nf * 16 + r15];
      sl[nf] = sv[nf * 16 + r15];
    }
#pragma unroll
    for (int mf = 0; mf < 4; ++mf) {
      float vb[4][4];
#pragma unroll
      for (int nf = 0; nf < 4; ++nf)
#pragma unroll
        for (int rg = 0; rg < 4; ++rg)
          vb[nf][rg] = acc[mf][nf][rg] + bj4[nf];
#pragma unroll
      for (int rg = 0; rg < 4; ++rg) {
        float ss = vb[0][rg] * vb[0][rg];
        ss = __builtin_fmaf(vb[1][rg], vb[1][rg], ss);
        ss = __builtin_fmaf(vb[2][rg], vb[2][rg], ss);
        ss = __builtin_fmaf(vb[3][rg], vb[3][rg], ss);
        ss += __shfl_xor(ss, 1); ss += __shfl_xor(ss, 2);
        ss += __shfl_xor(ss, 4); ss += __shfl_xor(ss, 8);
        float f = rsqrtf(ss * (1.f / 64.f) + 1e-6f);
        int i = m0 + wm * 64 + mf * 16 + 4 * g + rg;
        int b = i >> rpbs;
        int pos = (i & rpbm) + posoff;
        short* dst = dstb + ((size_t)((b * 16 + hh) * kNT + pos)) * 64;
#pragma unroll
        for (int nf = 0; nf < 4; ++nf)
          dst[nf * 16 + r15] = f2bf(vb[nf][rg] * f * sl[nf]);
      }
    }
  }
}

// ---------- Flash attention: QBLK=64 (4 waves x 16 q), shared KV, KVBLK=64, dbuf ----------
// S^T = K*Q^T (per-q state lane-local), O^T = V^T*P^T (P stays in registers).
// KV loop unrolled x2 (static buffers), LDS read offsets hoisted to VGPRs.
__global__ __launch_bounds__(256, 4) void k_attn(
    const short* __restrict__ Q, const short* __restrict__ K,
    const short* __restrict__ Vt, short* __restrict__ Ao) {
  __shared__ __align__(16) short Ks[2][4096];  // [kv][d], 8-grp src-swizzled
  __shared__ __align__(16) short Vs[2][4096];  // [d][kv'], kv' pre-permuted in global
  const int t = threadIdx.x;
  const int lane = t & 63, w = t >> 6;
  const int g = lane >> 4, r15 = lane & 15;
  const int bh = blockIdx.y;
  const int q0 = blockIdx.x * 64;
  const float csc = 0.125f * 1.44269504f;  // scale * log2(e)

  // Q B-fragments (q = q0 + 16w + r15): element j -> d = 8g + j + 32ks
  const short* qrow = Q + ((size_t)bh * kNT + q0 + 16 * w + r15) * kD;
  s16x8 qf0 = *(const s16x8*)(qrow + 8 * g);
  s16x8 qf1 = *(const s16x8*)(qrow + 32 + 8 * g);

  const short* kptr[2]; const short* vptr[2];
  int sbase[2];
#pragma unroll
  for (int it = 0; it < 2; ++it) {
    int slot = t + 256 * it;
    int row = slot >> 3, gp = slot & 7;
    int gl = gp ^ (row & 7);
    kptr[it] = K + ((size_t)bh * kNT + row) * kD + 8 * gl;
    vptr[it] = Vt + ((size_t)bh * kD + row) * kNT + 8 * gl;
    sbase[it] = (256 * it + 64 * w) * 8;
  }

  // hoisted LDS read offsets (element units) — loop-invariant VGPRs
  int ko[2][4], vo[2][4];
#pragma unroll
  for (int a = 0; a < 2; ++a)
#pragma unroll
    for (int rf = 0; rf < 4; ++rf) {
      int row = 16 * rf + r15;
      ko[a][rf] = row * 64 + (((g + 4 * a) ^ (row & 7)) * 8);
      vo[a][rf] = row * 64 + (((4 * a + g) ^ (row & 7)) * 8);
    }

  f32x4 ot[4] = {};
  float m = -1e30f, l = 0.f;
  short* Ksf = &Ks[0][0]; short* Vsf = &Vs[0][0];

  // prologue: stage tile 0 into buffer 0
#pragma unroll
  for (int it = 0; it < 2; ++it) {
    gll16(kptr[it], Ksf + sbase[it]);
    gll16(vptr[it], Vsf + sbase[it]);
  }

  auto tile = [&](const short* Kb, const short* Vb, short* kst, short* vst, bool pref) {
    __syncthreads();  // drains our gll (vmcnt) + all waves' reads of dst buffer
    if (pref) {
#pragma unroll
      for (int it = 0; it < 2; ++it) {
        kptr[it] += 64 * kD; vptr[it] += 64;
        gll16(kptr[it], kst + sbase[it]);
        gll16(vptr[it], vst + sbase[it]);
      }
    }
    // S^T = K * Q^T
    f32x4 st[4] = {};
    __builtin_amdgcn_s_setprio(1);
#pragma unroll
    for (int a = 0; a < 2; ++a) {
      s16x8 qk = a ? qf1 : qf0;
#pragma unroll
      for (int rf = 0; rf < 4; ++rf) {
        s16x8 kf = *(const s16x8*)(Kb + ko[a][rf]);
        st[rf] = __builtin_amdgcn_mfma_f32_16x16x32_bf16(kf, qk, st[rf], 0, 0, 0);
      }
    }
    __builtin_amdgcn_s_setprio(0);
    // online softmax (max3-fusable tree)
    float t0 = fmaxf(fmaxf(st[0][0], st[0][1]), st[0][2]);
    float t1 = fmaxf(fmaxf(st[0][3], st[1][0]), st[1][1]);
    float t2 = fmaxf(fmaxf(st[1][2], st[1][3]), st[2][0]);
    float t3 = fmaxf(fmaxf(st[2][1], st[2][2]), st[2][3]);
    float t4 = fmaxf(fmaxf(st[3][0], st[3][1]), st[3][2]);
    float pm = fmaxf(fmaxf(fmaxf(t0, t1), t2), fmaxf(fmaxf(t3, t4), st[3][3]));
    pm = fmaxf(pm, __shfl_xor(pm, 16));
    pm = fmaxf(pm, __shfl_xor(pm, 32));
    int skip = __all(pm - m <= 16.0f);  // defer-max: p bounded by 2^2.9
    float mn = skip ? m : fmaxf(m, pm);
    float nmc = -mn * csc;
    float pv[4][4]; float rs4[4];
#pragma unroll
    for (int rf = 0; rf < 4; ++rf) {
#pragma unroll
      for (int j = 0; j < 4; ++j)
        pv[rf][j] = __builtin_amdgcn_exp2f(__builtin_fmaf(st[rf][j], csc, nmc));
      rs4[rf] = (pv[rf][0] + pv[rf][1]) + (pv[rf][2] + pv[rf][3]);
    }
    float rs = (rs4[0] + rs4[1]) + (rs4[2] + rs4[3]);
    rs += __shfl_xor(rs, 16);
    rs += __shfl_xor(rs, 32);
    if (!skip) {
      float alpha = __builtin_amdgcn_exp2f(__builtin_fmaf(m, csc, nmc));
      l *= alpha;
#pragma unroll
      for (int mf = 0; mf < 4; ++mf) {
        ot[mf][0] *= alpha; ot[mf][1] *= alpha;
        ot[mf][2] *= alpha; ot[mf][3] *= alpha;
      }
      m = mn;
    }
    l += rs;
    // P^T pack: element j <-> kv = 32c + 4g + (j&3) + 16*(j>>2)
    s16x8 pf[2];
#pragma unroll
    for (int c = 0; c < 2; ++c) {
      union { uint32_t u[4]; s16x8 v; } pk;
      pk.u[0] = cvtpk(pv[2 * c][0], pv[2 * c][1]);
      pk.u[1] = cvtpk(pv[2 * c][2], pv[2 * c][3]);
      pk.u[2] = cvtpk(pv[2 * c + 1][0], pv[2 * c + 1][1]);
      pk.u[3] = cvtpk(pv[2 * c + 1][2], pv[2 * c + 1][3]);
      pf[c] = pk.v;
    }
    // O^T += V^T * P^T
    __builtin_amdgcn_s_setprio(1);
#pragma unroll
    for (int mf = 0; mf < 4; ++mf)
#pragma unroll
      for (int c = 0; c < 2; ++c) {
        s16x8 vf = *(const s16x8*)(Vb + vo[c][mf]);
        ot[mf] = __builtin_amdgcn_mfma_f32_16x16x32_bf16(vf, pf[c], ot[mf], 0, 0, 0);
      }
    __builtin_amdgcn_s_setprio(0);
  };

  for (int pp = 0; pp < 18; ++pp) {
    tile(Ksf, Vsf, Ksf + 4096, Vsf + 4096, true);
    tile(Ksf + 4096, Vsf + 4096, Ksf, Vsf, pp != 17);
  }

  // epilogue: transpose O^T -> O via LDS (reuse Ks as f32), coalesced bf16 store
  __syncthreads();
  float* Os = (float*)&Ks[0][0];  // 4096 floats = 16 KiB, [wave][16 q][64 d] XOR-swizzled
  float rl = 1.f / l;
#pragma unroll
  for (int mf = 0; mf < 4; ++mf)
#pragma unroll
    for (int rg = 0; rg < 4; ++rg) {
      int d = 16 * mf + 4 * g + rg;
      Os[w * 1024 + r15 * 64 + (d ^ ((r15 & 7) << 3))] = ot[mf][rg] * rl;
    }
  __syncthreads();
  {
    int w2 = t >> 6, ql = (t & 63) >> 2, c4 = t & 3;
    int b = bh >> 4, h = bh & 15;
    float vals[16];
#pragma unroll
    for (int i = 0; i < 4; ++i) {
      f32x4 rd = *(const f32x4*)&Os[w2 * 1024 + ql * 64 + (((c4 * 16 + 4 * i) ^ ((ql & 7) << 3)))];
      vals[4 * i + 0] = rd[0]; vals[4 * i + 1] = rd[1];
      vals[4 * i + 2] = rd[2]; vals[4 * i + 3] = rd[3];
    }
    union { uint32_t u[4]; s16x8 v; } o0, o1;
    o0.u[0] = cvtpk(vals[0], vals[1]);   o0.u[1] = cvtpk(vals[2], vals[3]);
    o0.u[2] = cvtpk(vals[4], vals[5]);   o0.u[3] = cvtpk(vals[6], vals[7]);
    o1.u[0] = cvtpk(vals[8], vals[9]);   o1.u[1] = cvtpk(vals[10], vals[11]);
    o1.u[2] = cvtpk(vals[12], vals[13]); o1.u[3] = cvtpk(vals[14], vals[15]);
    short* dst = Ao + ((size_t)b * kNT + q0 + 16 * w2 + ql) * kDIM + h * kD + c4 * 16;
    *(s16x8*)dst = o0.v;
    *(s16x8*)(dst + 8) = o1.v;
  }
}

extern "C" void kernel_launch(void* const* d_in, const int* in_sizes, int n_in,
                              void* d_out, int out_size, void* d_ws, size_t ws_size,
                              hipStream_t stream) {
  const float* x   = (const float*)d_in[0];
  const float* c   = (const float*)d_in[1];
  const float* wqx = (const float*)d_in[2];
  const float* bqx = (const float*)d_in[3];
  const float* wqc = (const float*)d_in[4];
  const float* bqc = (const float*)d_in[5];
  const float* sqx = (const float*)d_in[6];
  const float* skx = (const float*)d_in[7];
  const float* sqc = (const float*)d_in[8];
  const float* skc = (const float*)d_in[9];
  const float* wpx = (const float*)d_in[10];
  const float* bpx = (const float*)d_in[11];
  const float* wpc = (const float*)d_in[12];
  const float* bpc = (const float*)d_in[13];
  float* out = (float*)d_out;

  char* p = (char*)d_ws;
  short* xb   = (short*)p; p += (size_t)4096 * 1024 * 2;
  short* cb   = (short*)p; p += (size_t)512 * 1024 * 2;
  short* wqxt = (short*)p; p += (size_t)3072 * 1024 * 2;
  short* wqct = (short*)p; p += (size_t)3072 * 1024 * 2;
  short* wpxt = (short*)p; p += (size_t)1024 * 1024 * 2;
  short* wpct = (short*)p; p += (size_t)1024 * 1024 * 2;
  short* qb   = (short*)p; p += (size_t)32 * 2304 * 64 * 2;
  short* kb   = (short*)p; p += (size_t)32 * 2304 * 64 * 2;
  short* vtb  = (short*)p; p += (size_t)32 * 64 * 2304 * 2;
  short* ao   = (short*)p; p += (size_t)2 * 2304 * 1024 * 2;

  k_cast2<<<4608, 256, 0, stream>>>(x, xb, c, cb, 4096);
  k_tcast2<<<dim3(96, 32, 2), dim3(32, 8), 0, stream>>>(wqx, wqxt, wqc, wqct, 1024, 3072);
  k_tcast2<<<dim3(32, 32, 2), dim3(32, 8), 0, stream>>>(wpx, wpxt, wpc, wpct, 1024, 1024);

  // QKV projections (+bias, fused RMSNorm), q/k -> [BH][pos][64], v -> [BH][64][pos'] permuted
  k_gemm<<<dim3(24, 36), 256, 0, stream>>>(
      xb, wqxt, bqx, sqx, skx,
      cb, wqct, bqc, sqc, skc,
      qb, kb, vtb, nullptr, nullptr,
      11, 2048, 0, 0,
      8, 256, 0, 2048,
      32, 0);

  k_attn<<<dim3(36, 32), 256, 0, stream>>>(qb, kb, vtb, ao);

  // output projections (f32 + bias) straight into d_out
  k_gemm<<<dim3(8, 36), 256, 0, stream>>>(
      ao, wpxt, bpx, nullptr, nullptr,
      ao, wpct, bpc, nullptr, nullptr,
      nullptr, nullptr, nullptr, out, out + (size_t)4096 * 1024,
      11, 2304, 0, 0,
      8, 2304, 2048, 0,
      32, 1);
}

// Round 4
// 212.916 us; speedup vs baseline: 2.0676x; 1.0280x over previous
//
#include <hip/hip_runtime.h>
#include <stdint.h>

typedef __attribute__((ext_vector_type(4))) float  f32x4;
typedef __attribute__((ext_vector_type(8))) short  s16x8;
typedef __attribute__((ext_vector_type(4))) short  s16x4;

constexpr int kDIM = 1024;
constexpr int kD   = 64;
constexpr int kNT  = 2304;   // Nx + Nc

static __device__ __forceinline__ float bf2f(short u) {
  union { float f; uint32_t i; } x; x.i = ((uint32_t)(uint16_t)u) << 16; return x.f;
}
static __device__ __forceinline__ short f2bf(float f) {
  union { float f; uint32_t i; } x; x.f = f;
  uint32_t r = x.i + 0x7fffu + ((x.i >> 16) & 1u);
  return (short)(r >> 16);
}
static __device__ __forceinline__ uint32_t cvtpk(float lo, float hi) {
  uint32_t r;
  asm volatile("v_cvt_pk_bf16_f32 %0, %1, %2" : "=v"(r) : "v"(lo), "v"(hi));
  return r;
}
// async global->LDS, 16B per lane; LDS dest = wave-uniform base + lane*16
static __device__ __forceinline__ void gll16(const short* g, short* l) {
  __builtin_amdgcn_global_load_lds((const __attribute__((address_space(1))) void*)g,
                                   (__attribute__((address_space(3))) void*)l, 16, 0, 0);
}

// ---------- cast f32 -> bf16 (x and c in one launch) ----------
__global__ __launch_bounds__(256) void k_cast2(const float* __restrict__ x,
                                               short* __restrict__ xb,
                                               const float* __restrict__ c,
                                               short* __restrict__ cb, int nxb) {
  int b = blockIdx.x;
  const float* in = x; short* out = xb;
  if (b >= nxb) { in = c; out = cb; b -= nxb; }
  int i = (b * 256 + threadIdx.x) * 4;
  f32x4 v = *(const f32x4*)(in + i);
  s16x4 o; o[0] = f2bf(v[0]); o[1] = f2bf(v[1]); o[2] = f2bf(v[2]); o[3] = f2bf(v[3]);
  *(s16x4*)(out + i) = o;
}

// ---------- transpose+cast: W[K][N] f32 -> Wt[N][K] bf16, two weights per launch ----------
__global__ __launch_bounds__(256) void k_tcast2(const float* __restrict__ W0,
                                                short* __restrict__ Wt0,
                                                const float* __restrict__ W1,
                                                short* __restrict__ Wt1,
                                                int K, int N) {
  const float* W = blockIdx.z ? W1 : W0;
  short* Wt = blockIdx.z ? Wt1 : Wt0;
  __shared__ float tile[32][33];
  int n0 = blockIdx.x * 32, k0 = blockIdx.y * 32;
  int tx = threadIdx.x, ty = threadIdx.y;
#pragma unroll
  for (int i2 = 0; i2 < 4; ++i2) {
    int r = ty + 8 * i2;
    tile[r][tx] = W[(size_t)(k0 + r) * N + n0 + tx];
  }
  __syncthreads();
#pragma unroll
  for (int i2 = 0; i2 < 4; ++i2) {
    int r = ty + 8 * i2;
    Wt[(size_t)(n0 + r) * K + k0 + tx] = f2bf(tile[tx][r]);
  }
}

// ---------- GEMM: C = A * Wt^T + bias, two param-sets per launch (1-D grid, XCD swz) ----------
// epi==0: N=3072, fused RMSNorm on q/k heads (q gets extra 0.125*log2e), v transposed+permuted
// epi==1: N=1024, f32 rows to outp
__global__ __launch_bounds__(256) void k_gemm(
    const short* A0, const short* Wt0, const float* bias0,
    const float* sq0, const float* sk0,
    const short* A1, const short* Wt1, const float* bias1,
    const float* sq1, const float* sk1,
    short* outq, short* outk, short* outvt,
    float* outp0, float* outp1,
    int rpbs0, int arstride0, int aoff0, int posoff0,
    int rpbs1, int arstride1, int aoff1, int posoff1,
    int ybreak, int epi, int nx) {
  __shared__ __align__(16) short As[128 * 64];
  __shared__ __align__(16) short Bs[128 * 64];
  const int t = threadIdx.x;
  const int lane = t & 63, w = t >> 6;
  const int g = lane >> 4, r15 = lane & 15;
  const int wm = w >> 1, wn = w & 1;

  // bijective XCD swizzle (nwg % 8 == 0)
  int lin = blockIdx.x;
  int nwg = gridDim.x;
  int swz = (lin & 7) * (nwg >> 3) + (lin >> 3);
  int bx = swz % nx;
  int by = swz / nx;

  const short* A; const short* Wt; const float* bias;
  const float* sq; const float* sk; float* outp;
  int rpbs, arstride, aoff, posoff, my;
  if (by < ybreak) {
    A = A0; Wt = Wt0; bias = bias0; sq = sq0; sk = sk0; outp = outp0;
    rpbs = rpbs0; arstride = arstride0; aoff = aoff0; posoff = posoff0; my = by;
  } else {
    A = A1; Wt = Wt1; bias = bias1; sq = sq1; sk = sk1; outp = outp1;
    rpbs = rpbs1; arstride = arstride1; aoff = aoff1; posoff = posoff1; my = by - ybreak;
  }
  const int m0 = my * 128, n0 = bx * 128;

  const short* aptr[4]; const short* bptr[4];
  short* alds[4]; short* blds[4];
#pragma unroll
  for (int it = 0; it < 4; ++it) {
    int slot = t + 256 * it;
    int row = slot >> 3, gp = slot & 7;
    int gl = gp ^ (row & 7);               // pre-swizzled source group
    int i = m0 + row;
    int arow = (i >> rpbs) * arstride + aoff + (i & ((1 << rpbs) - 1));
    aptr[it] = A + (size_t)arow * kDIM + 8 * gl;
    bptr[it] = Wt + (size_t)(n0 + row) * kDIM + 8 * gl;
    int wbase = (256 * it + 64 * w) * 8;   // wave-uniform LDS slot base (shorts)
    alds[it] = As + wbase;
    blds[it] = Bs + wbase;
  }

  f32x4 acc[4][4] = {};

  for (int kt = 0; kt < 16; ++kt) {
#pragma unroll
    for (int it = 0; it < 4; ++it) {
      gll16(aptr[it], alds[it]);
      gll16(bptr[it], blds[it]);
      aptr[it] += 64; bptr[it] += 64;
    }
    __syncthreads();
#pragma unroll
    for (int ks = 0; ks < 2; ++ks) {
      s16x8 af[4], bfr[4];
#pragma unroll
      for (int mf = 0; mf < 4; ++mf) {
        int row = wm * 64 + mf * 16 + r15;
        af[mf] = *(const s16x8*)(As + row * 64 + (((g + 4 * ks) ^ (row & 7)) * 8));
      }
#pragma unroll
      for (int nf = 0; nf < 4; ++nf) {
        int row = wn * 64 + nf * 16 + r15;
        bfr[nf] = *(const s16x8*)(Bs + row * 64 + (((g + 4 * ks) ^ (row & 7)) * 8));
      }
#pragma unroll
      for (int mf = 0; mf < 4; ++mf)
#pragma unroll
        for (int nf = 0; nf < 4; ++nf)
          acc[mf][nf] = __builtin_amdgcn_mfma_f32_16x16x32_bf16(af[mf], bfr[nf], acc[mf][nf], 0, 0, 0);
    }
    __syncthreads();
  }

  const int rpbm = (1 << rpbs) - 1;
  if (epi == 1) {
#pragma unroll
    for (int mf = 0; mf < 4; ++mf)
#pragma unroll
      for (int nf = 0; nf < 4; ++nf) {
        int i = m0 + wm * 64 + mf * 16 + 4 * g;
        int j = n0 + wn * 64 + nf * 16 + r15;
        f32x4 v = acc[mf][nf];
        float bj = bias[j];
#pragma unroll
        for (int rg = 0; rg < 4; ++rg)
          outp[(size_t)(i + rg) * 1024 + j] = v[rg] + bj;
      }
    return;
  }
  const int eblk = (n0 + wn * 64) >> 10;   // wave-uniform: 0=q, 1=k, 2=v
  const int hh = ((n0 + wn * 64) >> 6) & 15;
  if (eblk == 2) {
#pragma unroll
    for (int mf = 0; mf < 4; ++mf)
#pragma unroll
      for (int nf = 0; nf < 4; ++nf) {
        int i = m0 + wm * 64 + mf * 16 + 4 * g;
        int j = n0 + wn * 64 + nf * 16 + r15;
        f32x4 v = acc[mf][nf];
        float bj = bias[j];
        int d = j & 63;
        int b = i >> rpbs;
        int pos = (i & rpbm) + posoff;
        // permuted column order within each 64-block (keeps low 2 bits):
        int pg = (pos & ~63) | (pos & 32) | (((pos >> 2) & 3) << 3) |
                 (((pos >> 4) & 1) << 2) | (pos & 3);
        size_t base = ((size_t)((b * 16 + hh) * 64 + d)) * kNT + pg;
        s16x4 o;
        o[0] = f2bf(v[0] + bj); o[1] = f2bf(v[1] + bj);
        o[2] = f2bf(v[2] + bj); o[3] = f2bf(v[3] + bj);
        *(s16x4*)(outvt + base) = o;
      }
  } else {
    const float* sv = (eblk == 0) ? sq : sk;
    short* dstb = (eblk == 0) ? outq : outk;
    // fold attention scale*log2(e) into q (softmax becomes raw exp2)
    const float post = (eblk == 0) ? 0.125f * 1.44269504f : 1.0f;
    float sl[4], bj4[4];
#pragma unroll
    for (int nf = 0; nf < 4; ++nf) {
      bj4[nf] = bias[n0 + wn * 64 + nf * 16 + r15];
      sl[nf] = sv[nf * 16 + r15] * post;
    }
#pragma unroll
    for (int mf = 0; mf < 4; ++mf) {
      float vb[4][4];
#pragma unroll
      for (int nf = 0; nf < 4; ++nf)
#pragma unroll
        for (int rg = 0; rg < 4; ++rg)
          vb[nf][rg] = acc[mf][nf][rg] + bj4[nf];
#pragma unroll
      for (int rg = 0; rg < 4; ++rg) {
        float ss = vb[0][rg] * vb[0][rg];
        ss = __builtin_fmaf(vb[1][rg], vb[1][rg], ss);
        ss = __builtin_fmaf(vb[2][rg], vb[2][rg], ss);
        ss = __builtin_fmaf(vb[3][rg], vb[3][rg], ss);
        ss += __shfl_xor(ss, 1); ss += __shfl_xor(ss, 2);
        ss += __shfl_xor(ss, 4); ss += __shfl_xor(ss, 8);
        float f = rsqrtf(ss * (1.f / 64.f) + 1e-6f);
        int i = m0 + wm * 64 + mf * 16 + 4 * g + rg;
        int b = i >> rpbs;
        int pos = (i & rpbm) + posoff;
        short* dst = dstb + ((size_t)((b * 16 + hh) * kNT + pos)) * 64;
#pragma unroll
        for (int nf = 0; nf < 4; ++nf)
          dst[nf * 16 + r15] = f2bf(vb[nf][rg] * f * sl[nf]);
      }
    }
  }
}

// ---------- Flash attention: 2 waves x 32 q, shared KV (dbuf, KVBLK=64) ----------
// No-max softmax (RMSNorm bounds |score*log2e| <= 11.6): p = exp2(S^T), zero
// cross-lane ops in the loop. S^T = K*Q^T; O^T = V^T*P^T (P in registers).
// XCD-aware head placement: each head's 36 q-blocks land on one XCD.
__global__ __launch_bounds__(128, 3) void k_attn(
    const short* __restrict__ Q, const short* __restrict__ K,
    const short* __restrict__ Vt, short* __restrict__ Ao) {
  __shared__ __align__(16) short Ks[2][4096];  // [kv][d], 8-grp src-swizzled
  __shared__ __align__(16) short Vs[2][4096];  // [d][kv'], kv' pre-permuted in global
  const int t = threadIdx.x;
  const int lane = t & 63, w = t >> 6;
  const int g = lane >> 4, r15 = lane & 15;
  // head/qblock decode: lin&7 = XCD; 4 heads per XCD, 36 q-blocks per head
  const int lin = blockIdx.x;
  const int idx = lin >> 3;
  const int bh = (lin & 7) * 4 + idx / 36;
  const int q0 = (idx % 36) * 64;

  // Q B-fragments, 2 per wave (q = q0 + 32w + 16qi + r15); elem j -> d = 8g+j+32a
  s16x8 qf[2][2];
#pragma unroll
  for (int qi = 0; qi < 2; ++qi) {
    const short* qrow = Q + ((size_t)bh * kNT + q0 + 32 * w + 16 * qi + r15) * kD;
    qf[qi][0] = *(const s16x8*)(qrow + 8 * g);
    qf[qi][1] = *(const s16x8*)(qrow + 32 + 8 * g);
  }

  const short* kptr[4]; const short* vptr[4];
  int sbase[4];
#pragma unroll
  for (int it = 0; it < 4; ++it) {
    int slot = t + 128 * it;
    int row = slot >> 3, gp = slot & 7;
    int gl = gp ^ (row & 7);
    kptr[it] = K + ((size_t)bh * kNT + row) * kD + 8 * gl;
    vptr[it] = Vt + ((size_t)bh * kD + row) * kNT + 8 * gl;
    sbase[it] = (128 * it + 64 * w) * 8;
  }

  // hoisted LDS read offsets (element units)
  int ko[2][4], vo[2][4];
#pragma unroll
  for (int a = 0; a < 2; ++a)
#pragma unroll
    for (int rf = 0; rf < 4; ++rf) {
      int row = 16 * rf + r15;
      ko[a][rf] = row * 64 + (((g + 4 * a) ^ (row & 7)) * 8);
      vo[a][rf] = row * 64 + (((4 * a + g) ^ (row & 7)) * 8);
    }

  f32x4 ot0[4] = {}, ot1[4] = {};
  float l0 = 0.f, l1 = 0.f;
  short* Ksf = &Ks[0][0]; short* Vsf = &Vs[0][0];

  // prologue: stage tile 0 into buffer 0
#pragma unroll
  for (int it = 0; it < 4; ++it) {
    gll16(kptr[it], Ksf + sbase[it]);
    gll16(vptr[it], Vsf + sbase[it]);
  }

  auto tile = [&](const short* Kb, const short* Vb, short* kst, short* vst, bool pref) {
    __syncthreads();  // drains our gll (vmcnt) + all waves' reads of dst buffer
    if (pref) {
#pragma unroll
      for (int it = 0; it < 4; ++it) {
        kptr[it] += 64 * kD; vptr[it] += 64;
        gll16(kptr[it], kst + sbase[it]);
        gll16(vptr[it], vst + sbase[it]);
      }
    }
    // S^T = K * Q^T for both q-frags (K frags shared)
    f32x4 st0[4] = {}, st1[4] = {};
    __builtin_amdgcn_s_setprio(1);
#pragma unroll
    for (int a = 0; a < 2; ++a) {
#pragma unroll
      for (int rf = 0; rf < 4; ++rf) {
        s16x8 kf = *(const s16x8*)(Kb + ko[a][rf]);
        st0[rf] = __builtin_amdgcn_mfma_f32_16x16x32_bf16(kf, qf[0][a], st0[rf], 0, 0, 0);
        st1[rf] = __builtin_amdgcn_mfma_f32_16x16x32_bf16(kf, qf[1][a], st1[rf], 0, 0, 0);
      }
    }
    __builtin_amdgcn_s_setprio(0);
    // softmax: pure exp2 (scale folded into q), lane-local l accumulation
    float pv0[4][4], pv1[4][4];
#pragma unroll
    for (int rf = 0; rf < 4; ++rf)
#pragma unroll
      for (int j = 0; j < 4; ++j) {
        pv0[rf][j] = __builtin_amdgcn_exp2f(st0[rf][j]);
        pv1[rf][j] = __builtin_amdgcn_exp2f(st1[rf][j]);
        l0 += pv0[rf][j];
        l1 += pv1[rf][j];
      }
    // P^T pack: element j <-> kv = 32c + 4g + (j&3) + 16*(j>>2)
    s16x8 pf0[2], pf1[2];
#pragma unroll
    for (int c = 0; c < 2; ++c) {
      union { uint32_t u[4]; s16x8 v; } a, b;
      a.u[0] = cvtpk(pv0[2 * c][0], pv0[2 * c][1]);
      a.u[1] = cvtpk(pv0[2 * c][2], pv0[2 * c][3]);
      a.u[2] = cvtpk(pv0[2 * c + 1][0], pv0[2 * c + 1][1]);
      a.u[3] = cvtpk(pv0[2 * c + 1][2], pv0[2 * c + 1][3]);
      pf0[c] = a.v;
      b.u[0] = cvtpk(pv1[2 * c][0], pv1[2 * c][1]);
      b.u[1] = cvtpk(pv1[2 * c][2], pv1[2 * c][3]);
      b.u[2] = cvtpk(pv1[2 * c + 1][0], pv1[2 * c + 1][1]);
      b.u[3] = cvtpk(pv1[2 * c + 1][2], pv1[2 * c + 1][3]);
      pf1[c] = b.v;
    }
    // O^T += V^T * P^T (V frags shared by both q-frags)
    __builtin_amdgcn_s_setprio(1);
#pragma unroll
    for (int mf = 0; mf < 4; ++mf)
#pragma unroll
      for (int c = 0; c < 2; ++c) {
        s16x8 vf = *(const s16x8*)(Vb + vo[c][mf]);
        ot0[mf] = __builtin_amdgcn_mfma_f32_16x16x32_bf16(vf, pf0[c], ot0[mf], 0, 0, 0);
        ot1[mf] = __builtin_amdgcn_mfma_f32_16x16x32_bf16(vf, pf1[c], ot1[mf], 0, 0, 0);
      }
    __builtin_amdgcn_s_setprio(0);
  };

  for (int pp = 0; pp < 18; ++pp) {
    tile(Ksf, Vsf, Ksf + 4096, Vsf + 4096, true);
    tile(Ksf + 4096, Vsf + 4096, Ksf, Vsf, pp != 17);
  }

  // cross-g l reduction (once)
  l0 += __shfl_xor(l0, 16); l0 += __shfl_xor(l0, 32);
  l1 += __shfl_xor(l1, 16); l1 += __shfl_xor(l1, 32);
  float rl0 = 1.f / l0, rl1 = 1.f / l1;

  // epilogue: transpose O^T -> O via LDS (reuse Ks as f32), coalesced bf16 store
  __syncthreads();
  float* Os = (float*)&Ks[0][0];  // 4096 floats = 16 KiB, rows R=[0,64) x 64 d, XOR-swz
#pragma unroll
  for (int mf = 0; mf < 4; ++mf)
#pragma unroll
    for (int rg = 0; rg < 4; ++rg) {
      int d = 16 * mf + 4 * g + rg;
      int R0 = 32 * w + r15, R1 = 32 * w + 16 + r15;
      Os[R0 * 64 + (d ^ ((r15 & 7) << 3))] = ot0[mf][rg] * rl0;
      Os[R1 * 64 + (d ^ ((r15 & 7) << 3))] = ot1[mf][rg] * rl1;
    }
  __syncthreads();
  {
    int b = bh >> 4, h = bh & 15;
#pragma unroll
    for (int rep = 0; rep < 2; ++rep) {
      int idx = t + 128 * rep;
      int q = idx >> 2, c4 = idx & 3;
      float vals[16];
#pragma unroll
      for (int i = 0; i < 4; ++i) {
        f32x4 rd = *(const f32x4*)&Os[q * 64 + (((c4 * 16 + 4 * i) ^ ((q & 7) << 3)))];
        vals[4 * i + 0] = rd[0]; vals[4 * i + 1] = rd[1];
        vals[4 * i + 2] = rd[2]; vals[4 * i + 3] = rd[3];
      }
      union { uint32_t u[4]; s16x8 v; } o0, o1;
      o0.u[0] = cvtpk(vals[0], vals[1]);   o0.u[1] = cvtpk(vals[2], vals[3]);
      o0.u[2] = cvtpk(vals[4], vals[5]);   o0.u[3] = cvtpk(vals[6], vals[7]);
      o1.u[0] = cvtpk(vals[8], vals[9]);   o1.u[1] = cvtpk(vals[10], vals[11]);
      o1.u[2] = cvtpk(vals[12], vals[13]); o1.u[3] = cvtpk(vals[14], vals[15]);
      short* dst = Ao + ((size_t)b * kNT + q0 + q) * kDIM + h * kD + c4 * 16;
      *(s16x8*)dst = o0.v;
      *(s16x8*)(dst + 8) = o1.v;
    }
  }
}

extern "C" void kernel_launch(void* const* d_in, const int* in_sizes, int n_in,
                              void* d_out, int out_size, void* d_ws, size_t ws_size,
                              hipStream_t stream) {
  const float* x   = (const float*)d_in[0];
  const float* c   = (const float*)d_in[1];
  const float* wqx = (const float*)d_in[2];
  const float* bqx = (const float*)d_in[3];
  const float* wqc = (const float*)d_in[4];
  const float* bqc = (const float*)d_in[5];
  const float* sqx = (const float*)d_in[6];
  const float* skx = (const float*)d_in[7];
  const float* sqc = (const float*)d_in[8];
  const float* skc = (const float*)d_in[9];
  const float* wpx = (const float*)d_in[10];
  const float* bpx = (const float*)d_in[11];
  const float* wpc = (const float*)d_in[12];
  const float* bpc = (const float*)d_in[13];
  float* out = (float*)d_out;

  char* p = (char*)d_ws;
  short* xb   = (short*)p; p += (size_t)4096 * 1024 * 2;
  short* cb   = (short*)p; p += (size_t)512 * 1024 * 2;
  short* wqxt = (short*)p; p += (size_t)3072 * 1024 * 2;
  short* wqct = (short*)p; p += (size_t)3072 * 1024 * 2;
  short* wpxt = (short*)p; p += (size_t)1024 * 1024 * 2;
  short* wpct = (short*)p; p += (size_t)1024 * 1024 * 2;
  short* qb   = (short*)p; p += (size_t)32 * 2304 * 64 * 2;
  short* kb   = (short*)p; p += (size_t)32 * 2304 * 64 * 2;
  short* vtb  = (short*)p; p += (size_t)32 * 64 * 2304 * 2;
  short* ao   = (short*)p; p += (size_t)2 * 2304 * 1024 * 2;

  k_cast2<<<4608, 256, 0, stream>>>(x, xb, c, cb, 4096);
  k_tcast2<<<dim3(96, 32, 2), dim3(32, 8), 0, stream>>>(wqx, wqxt, wqc, wqct, 1024, 3072);
  k_tcast2<<<dim3(32, 32, 2), dim3(32, 8), 0, stream>>>(wpx, wpxt, wpc, wpct, 1024, 1024);

  // QKV projections (+bias, fused RMSNorm; q pre-scaled by 0.125*log2e)
  k_gemm<<<864, 256, 0, stream>>>(
      xb, wqxt, bqx, sqx, skx,
      cb, wqct, bqc, sqc, skc,
      qb, kb, vtb, nullptr, nullptr,
      11, 2048, 0, 0,
      8, 256, 0, 2048,
      32, 0, 24);

  k_attn<<<1152, 128, 0, stream>>>(qb, kb, vtb, ao);

  // output projections (f32 + bias) straight into d_out
  k_gemm<<<288, 256, 0, stream>>>(
      ao, wpxt, bpx, nullptr, nullptr,
      ao, wpct, bpc, nullptr, nullptr,
      nullptr, nullptr, nullptr, out, out + (size_t)4096 * 1024,
      11, 2304, 0, 0,
      8, 2304, 2048, 0,
      32, 1, 8);
}

// Round 5
// 157.527 us; speedup vs baseline: 2.7946x; 1.3516x over previous
//
#include <hip/hip_runtime.h>
#include <stdint.h>

typedef __attribute__((ext_vector_type(4))) float  f32x4;
typedef __attribute__((ext_vector_type(8))) short  s16x8;
typedef __attribute__((ext_vector_type(4))) short  s16x4;

constexpr int kDIM = 1024;
constexpr int kD   = 64;
constexpr int kNT  = 2304;   // Nx + Nc

static __device__ __forceinline__ short f2bf(float f) {
  union { float f; uint32_t i; } x; x.f = f;
  uint32_t r = x.i + 0x7fffu + ((x.i >> 16) & 1u);
  return (short)(r >> 16);
}
static __device__ __forceinline__ uint32_t cvtpk(float lo, float hi) {
  uint32_t r;
  asm volatile("v_cvt_pk_bf16_f32 %0, %1, %2" : "=v"(r) : "v"(lo), "v"(hi));
  return r;
}
// async global->LDS, 16B per lane; LDS dest = wave-uniform base + lane*16
static __device__ __forceinline__ void gll16(const short* g, short* l) {
  __builtin_amdgcn_global_load_lds((const __attribute__((address_space(1))) void*)g,
                                   (__attribute__((address_space(3))) void*)l, 16, 0, 0);
}
#define FENCE() asm volatile("" ::: "memory")
#define WAITV8() asm volatile("s_waitcnt vmcnt(8)" ::: "memory")
#define WAITV0() asm volatile("s_waitcnt vmcnt(0)" ::: "memory")

// ---------- cast f32 -> bf16 (x and c in one launch) ----------
__global__ __launch_bounds__(256) void k_cast2(const float* __restrict__ x,
                                               short* __restrict__ xb,
                                               const float* __restrict__ c,
                                               short* __restrict__ cb, int nxb) {
  int b = blockIdx.x;
  const float* in = x; short* out = xb;
  if (b >= nxb) { in = c; out = cb; b -= nxb; }
  int i = (b * 256 + threadIdx.x) * 4;
  f32x4 v = *(const f32x4*)(in + i);
  s16x4 o; o[0] = f2bf(v[0]); o[1] = f2bf(v[1]); o[2] = f2bf(v[2]); o[3] = f2bf(v[3]);
  *(s16x4*)(out + i) = o;
}

// ---------- transpose+cast: W[K][N] f32 -> Wt[N][K] bf16, two weights per launch ----------
__global__ __launch_bounds__(256) void k_tcast2(const float* __restrict__ W0,
                                                short* __restrict__ Wt0,
                                                const float* __restrict__ W1,
                                                short* __restrict__ Wt1,
                                                int K, int N) {
  const float* W = blockIdx.z ? W1 : W0;
  short* Wt = blockIdx.z ? Wt1 : Wt0;
  __shared__ float tile[32][33];
  int n0 = blockIdx.x * 32, k0 = blockIdx.y * 32;
  int tx = threadIdx.x, ty = threadIdx.y;
#pragma unroll
  for (int i2 = 0; i2 < 4; ++i2) {
    int r = ty + 8 * i2;
    tile[r][tx] = W[(size_t)(k0 + r) * N + n0 + tx];
  }
  __syncthreads();
#pragma unroll
  for (int i2 = 0; i2 < 4; ++i2) {
    int r = ty + 8 * i2;
    Wt[(size_t)(n0 + r) * K + k0 + tx] = f2bf(tile[tx][r]);
  }
}

// ---------- GEMM: C = A * Wt^T + bias, two param-sets per launch ----------
// Double-buffered LDS + counted vmcnt (no vmcnt(0) drain in steady state).
// 2-D XCD chunking: each XCD owns a (9 by) x (nx/2 bx) chunk of the block grid.
// epi==0: N=3072, fused RMSNorm on q/k heads (q gets extra 0.125*log2e), v transposed+permuted
// epi==1: N=1024, f32 rows to outp
__global__ __launch_bounds__(256, 2) void k_gemm(
    const short* A0, const short* Wt0, const float* bias0,
    const float* sq0, const float* sk0,
    const short* A1, const short* Wt1, const float* bias1,
    const float* sq1, const float* sk1,
    short* outq, short* outk, short* outvt,
    float* outp0, float* outp1,
    int rpbs0, int arstride0, int aoff0, int posoff0,
    int rpbs1, int arstride1, int aoff1, int posoff1,
    int ybreak, int epi, int nx) {
  __shared__ __align__(16) short As[2][8192];
  __shared__ __align__(16) short Bs[2][8192];
  const int t = threadIdx.x;
  const int lane = t & 63, w = t >> 6;
  const int g = lane >> 4, r15 = lane & 15;
  const int wm = w >> 1, wn = w & 1;

  // 2-D XCD chunk decode: xcd = lin&7 owns rows [(xcd&3)*9, +9) x cols [(xcd>>2)*(nx/2), +nx/2)
  int lin = blockIdx.x;
  int xcd = lin & 7, kk = lin >> 3;
  int by = (xcd & 3) * 9 + kk % 9;
  int bx = (xcd >> 2) * (nx >> 1) + kk / 9;

  const short* A; const short* Wt; const float* bias;
  const float* sq; const float* sk; float* outp;
  int rpbs, arstride, aoff, posoff, my;
  if (by < ybreak) {
    A = A0; Wt = Wt0; bias = bias0; sq = sq0; sk = sk0; outp = outp0;
    rpbs = rpbs0; arstride = arstride0; aoff = aoff0; posoff = posoff0; my = by;
  } else {
    A = A1; Wt = Wt1; bias = bias1; sq = sq1; sk = sk1; outp = outp1;
    rpbs = rpbs1; arstride = arstride1; aoff = aoff1; posoff = posoff1; my = by - ybreak;
  }
  const int m0 = my * 128, n0 = bx * 128;

  const short* aptr[4]; const short* bptr[4];
  int wofs[4];
#pragma unroll
  for (int it = 0; it < 4; ++it) {
    int slot = t + 256 * it;
    int row = slot >> 3, gp = slot & 7;
    int gl = gp ^ (row & 7);               // pre-swizzled source group
    int i = m0 + row;
    int arow = (i >> rpbs) * arstride + aoff + (i & ((1 << rpbs) - 1));
    aptr[it] = A + (size_t)arow * kDIM + 8 * gl;
    bptr[it] = Wt + (size_t)(n0 + row) * kDIM + 8 * gl;
    wofs[it] = (256 * it + 64 * w) * 8;    // wave-uniform LDS slot base (shorts)
  }

  f32x4 acc[4][4] = {};

  auto STAGE = [&](short* Asd, short* Bsd) {
#pragma unroll
    for (int it = 0; it < 4; ++it) {
      gll16(aptr[it], Asd + wofs[it]);
      gll16(bptr[it], Bsd + wofs[it]);
      aptr[it] += 64; bptr[it] += 64;
    }
  };

  auto kstep = [&](const short* Ab, const short* Bb, short* Asd, short* Bsd,
                   bool last, bool pref) {
    if (last) WAITV0(); else WAITV8();      // tile's 8 loads landed (per-wave)
    __builtin_amdgcn_s_barrier();           // all waves' loads landed
    FENCE();
#pragma unroll
    for (int ks = 0; ks < 2; ++ks) {
      s16x8 af[4], bfr[4];
#pragma unroll
      for (int mf = 0; mf < 4; ++mf) {
        int row = wm * 64 + mf * 16 + r15;
        af[mf] = *(const s16x8*)(Ab + row * 64 + (((g + 4 * ks) ^ (row & 7)) * 8));
      }
#pragma unroll
      for (int nf = 0; nf < 4; ++nf) {
        int row = wn * 64 + nf * 16 + r15;
        bfr[nf] = *(const s16x8*)(Bb + row * 64 + (((g + 4 * ks) ^ (row & 7)) * 8));
      }
#pragma unroll
      for (int mf = 0; mf < 4; ++mf)
#pragma unroll
        for (int nf = 0; nf < 4; ++nf)
          acc[mf][nf] = __builtin_amdgcn_mfma_f32_16x16x32_bf16(af[mf], bfr[nf], acc[mf][nf], 0, 0, 0);
    }
    FENCE();
    __builtin_amdgcn_s_barrier();           // all waves done reading this buffer
    FENCE();
    if (pref) STAGE(Asd, Bsd);              // restage freed buffer (tile t+2)
  };

  // prologue: tiles 0,1 in flight (16 outstanding per wave)
  STAGE(&As[0][0], &Bs[0][0]);
  STAGE(&As[1][0], &Bs[1][0]);
  for (int pp = 0; pp < 8; ++pp) {
    kstep(&As[0][0], &Bs[0][0], &As[0][0], &Bs[0][0], false,   pp < 7);
    kstep(&As[1][0], &Bs[1][0], &As[1][0], &Bs[1][0], pp == 7, pp < 7);
  }

  const int rpbm = (1 << rpbs) - 1;
  if (epi == 1) {
#pragma unroll
    for (int mf = 0; mf < 4; ++mf)
#pragma unroll
      for (int nf = 0; nf < 4; ++nf) {
        int i = m0 + wm * 64 + mf * 16 + 4 * g;
        int j = n0 + wn * 64 + nf * 16 + r15;
        f32x4 v = acc[mf][nf];
        float bj = bias[j];
#pragma unroll
        for (int rg = 0; rg < 4; ++rg)
          outp[(size_t)(i + rg) * 1024 + j] = v[rg] + bj;
      }
    return;
  }
  const int eblk = (n0 + wn * 64) >> 10;   // wave-uniform: 0=q, 1=k, 2=v
  const int hh = ((n0 + wn * 64) >> 6) & 15;
  if (eblk == 2) {
#pragma unroll
    for (int mf = 0; mf < 4; ++mf)
#pragma unroll
      for (int nf = 0; nf < 4; ++nf) {
        int i = m0 + wm * 64 + mf * 16 + 4 * g;
        int j = n0 + wn * 64 + nf * 16 + r15;
        f32x4 v = acc[mf][nf];
        float bj = bias[j];
        int d = j & 63;
        int b = i >> rpbs;
        int pos = (i & rpbm) + posoff;
        // permuted column order within each 64-block (keeps low 2 bits):
        int pg = (pos & ~63) | (pos & 32) | (((pos >> 2) & 3) << 3) |
                 (((pos >> 4) & 1) << 2) | (pos & 3);
        size_t base = ((size_t)((b * 16 + hh) * 64 + d)) * kNT + pg;
        s16x4 o;
        o[0] = f2bf(v[0] + bj); o[1] = f2bf(v[1] + bj);
        o[2] = f2bf(v[2] + bj); o[3] = f2bf(v[3] + bj);
        *(s16x4*)(outvt + base) = o;
      }
  } else {
    const float* sv = (eblk == 0) ? sq : sk;
    short* dstb = (eblk == 0) ? outq : outk;
    // fold attention scale*log2(e) into q (softmax becomes raw exp2)
    const float post = (eblk == 0) ? 0.125f * 1.44269504f : 1.0f;
    float sl[4], bj4[4];
#pragma unroll
    for (int nf = 0; nf < 4; ++nf) {
      bj4[nf] = bias[n0 + wn * 64 + nf * 16 + r15];
      sl[nf] = sv[nf * 16 + r15] * post;
    }
#pragma unroll
    for (int mf = 0; mf < 4; ++mf) {
      float vb[4][4];
#pragma unroll
      for (int nf = 0; nf < 4; ++nf)
#pragma unroll
        for (int rg = 0; rg < 4; ++rg)
          vb[nf][rg] = acc[mf][nf][rg] + bj4[nf];
#pragma unroll
      for (int rg = 0; rg < 4; ++rg) {
        float ss = vb[0][rg] * vb[0][rg];
        ss = __builtin_fmaf(vb[1][rg], vb[1][rg], ss);
        ss = __builtin_fmaf(vb[2][rg], vb[2][rg], ss);
        ss = __builtin_fmaf(vb[3][rg], vb[3][rg], ss);
        ss += __shfl_xor(ss, 1); ss += __shfl_xor(ss, 2);
        ss += __shfl_xor(ss, 4); ss += __shfl_xor(ss, 8);
        float f = rsqrtf(ss * (1.f / 64.f) + 1e-6f);
        int i = m0 + wm * 64 + mf * 16 + 4 * g + rg;
        int b = i >> rpbs;
        int pos = (i & rpbm) + posoff;
        short* dst = dstb + ((size_t)((b * 16 + hh) * kNT + pos)) * 64;
#pragma unroll
        for (int nf = 0; nf < 4; ++nf)
          dst[nf * 16 + r15] = f2bf(vb[nf][rg] * f * sl[nf]);
      }
    }
  }
}

// ---------- Flash attention: 2 waves x 32 q, shared KV (dbuf, KVBLK=64) ----------
// No-max softmax (RMSNorm bounds |score*log2e| <= 11.6): p = exp2(S^T).
// Counted-vmcnt pipeline: never drain to 0; stage t+2 after the freeing barrier.
// XCD-aware head placement: each head's 36 q-blocks land on one XCD.
__global__ __launch_bounds__(128, 3) void k_attn(
    const short* __restrict__ Q, const short* __restrict__ K,
    const short* __restrict__ Vt, short* __restrict__ Ao) {
  __shared__ __align__(16) short Ks[2][4096];  // [kv][d], 8-grp src-swizzled
  __shared__ __align__(16) short Vs[2][4096];  // [d][kv'], kv' pre-permuted in global
  const int t = threadIdx.x;
  const int lane = t & 63, w = t >> 6;
  const int g = lane >> 4, r15 = lane & 15;
  // head/qblock decode: lin&7 = XCD; 4 heads per XCD, 36 q-blocks per head
  const int lin = blockIdx.x;
  const int idx = lin >> 3;
  const int bh = (lin & 7) * 4 + idx / 36;
  const int q0 = (idx % 36) * 64;

  // Q B-fragments, 2 per wave (q = q0 + 32w + 16qi + r15); elem j -> d = 8g+j+32a
  s16x8 qf[2][2];
#pragma unroll
  for (int qi = 0; qi < 2; ++qi) {
    const short* qrow = Q + ((size_t)bh * kNT + q0 + 32 * w + 16 * qi + r15) * kD;
    qf[qi][0] = *(const s16x8*)(qrow + 8 * g);
    qf[qi][1] = *(const s16x8*)(qrow + 32 + 8 * g);
  }

  const short* kptr[4]; const short* vptr[4];
  int sbase[4];
#pragma unroll
  for (int it = 0; it < 4; ++it) {
    int slot = t + 128 * it;
    int row = slot >> 3, gp = slot & 7;
    int gl = gp ^ (row & 7);
    kptr[it] = K + ((size_t)bh * kNT + row) * kD + 8 * gl;
    vptr[it] = Vt + ((size_t)bh * kD + row) * kNT + 8 * gl;
    sbase[it] = (128 * it + 64 * w) * 8;
  }

  // hoisted LDS read offsets (element units)
  int ko[2][4], vo[2][4];
#pragma unroll
  for (int a = 0; a < 2; ++a)
#pragma unroll
    for (int rf = 0; rf < 4; ++rf) {
      int row = 16 * rf + r15;
      ko[a][rf] = row * 64 + (((g + 4 * a) ^ (row & 7)) * 8);
      vo[a][rf] = row * 64 + (((4 * a + g) ^ (row & 7)) * 8);
    }

  f32x4 ot0[4] = {}, ot1[4] = {};
  float l0 = 0.f, l1 = 0.f;
  short* Ks0 = &Ks[0][0]; short* Ks1 = &Ks[1][0];
  short* Vs0 = &Vs[0][0]; short* Vs1 = &Vs[1][0];

  auto STAGE = [&](short* kst, short* vst) {
#pragma unroll
    for (int it = 0; it < 4; ++it) {
      gll16(kptr[it], kst + sbase[it]);
      gll16(vptr[it], vst + sbase[it]);
      kptr[it] += 64 * kD; vptr[it] += 64;
    }
  };

  auto tile = [&](const short* Kb, const short* Vb, short* kst, short* vst,
                  bool last, bool pref) {
    if (last) WAITV0(); else WAITV8();   // this tile's 8 loads landed (per-wave)
    __builtin_amdgcn_s_barrier();
    FENCE();
    // S^T = K * Q^T for both q-frags (K frags shared)
    f32x4 st0[4] = {}, st1[4] = {};
    __builtin_amdgcn_s_setprio(1);
#pragma unroll
    for (int a = 0; a < 2; ++a) {
#pragma unroll
      for (int rf = 0; rf < 4; ++rf) {
        s16x8 kf = *(const s16x8*)(Kb + ko[a][rf]);
        st0[rf] = __builtin_amdgcn_mfma_f32_16x16x32_bf16(kf, qf[0][a], st0[rf], 0, 0, 0);
        st1[rf] = __builtin_amdgcn_mfma_f32_16x16x32_bf16(kf, qf[1][a], st1[rf], 0, 0, 0);
      }
    }
    __builtin_amdgcn_s_setprio(0);
    // softmax: pure exp2 (scale folded into q), lane-local l accumulation
    float pv0[4][4], pv1[4][4];
#pragma unroll
    for (int rf = 0; rf < 4; ++rf)
#pragma unroll
      for (int j = 0; j < 4; ++j) {
        pv0[rf][j] = __builtin_amdgcn_exp2f(st0[rf][j]);
        pv1[rf][j] = __builtin_amdgcn_exp2f(st1[rf][j]);
        l0 += pv0[rf][j];
        l1 += pv1[rf][j];
      }
    // P^T pack: element j <-> kv = 32c + 4g + (j&3) + 16*(j>>2)
    s16x8 pf0[2], pf1[2];
#pragma unroll
    for (int c = 0; c < 2; ++c) {
      union { uint32_t u[4]; s16x8 v; } a, b;
      a.u[0] = cvtpk(pv0[2 * c][0], pv0[2 * c][1]);
      a.u[1] = cvtpk(pv0[2 * c][2], pv0[2 * c][3]);
      a.u[2] = cvtpk(pv0[2 * c + 1][0], pv0[2 * c + 1][1]);
      a.u[3] = cvtpk(pv0[2 * c + 1][2], pv0[2 * c + 1][3]);
      pf0[c] = a.v;
      b.u[0] = cvtpk(pv1[2 * c][0], pv1[2 * c][1]);
      b.u[1] = cvtpk(pv1[2 * c][2], pv1[2 * c][3]);
      b.u[2] = cvtpk(pv1[2 * c + 1][0], pv1[2 * c + 1][1]);
      b.u[3] = cvtpk(pv1[2 * c + 1][2], pv1[2 * c + 1][3]);
      pf1[c] = b.v;
    }
    // O^T += V^T * P^T (V frags shared by both q-frags)
    __builtin_amdgcn_s_setprio(1);
#pragma unroll
    for (int mf = 0; mf < 4; ++mf)
#pragma unroll
      for (int c = 0; c < 2; ++c) {
        s16x8 vf = *(const s16x8*)(Vb + vo[c][mf]);
        ot0[mf] = __builtin_amdgcn_mfma_f32_16x16x32_bf16(vf, pf0[c], ot0[mf], 0, 0, 0);
        ot1[mf] = __builtin_amdgcn_mfma_f32_16x16x32_bf16(vf, pf1[c], ot1[mf], 0, 0, 0);
      }
    __builtin_amdgcn_s_setprio(0);
    FENCE();
    __builtin_amdgcn_s_barrier();        // all waves done reading this buffer
    FENCE();
    if (pref) STAGE(kst, vst);           // restage freed buffer (tile t+2)
  };

  // prologue: tiles 0,1 in flight
  STAGE(Ks0, Vs0);
  STAGE(Ks1, Vs1);
  for (int pp = 0; pp < 18; ++pp) {
    tile(Ks0, Vs0, Ks0, Vs0, false,    pp < 17);
    tile(Ks1, Vs1, Ks1, Vs1, pp == 17, pp < 17);
  }

  // cross-g l reduction (once)
  l0 += __shfl_xor(l0, 16); l0 += __shfl_xor(l0, 32);
  l1 += __shfl_xor(l1, 16); l1 += __shfl_xor(l1, 32);
  float rl0 = 1.f / l0, rl1 = 1.f / l1;

  // epilogue: transpose O^T -> O via LDS (reuse Ks as f32), coalesced bf16 store
  __syncthreads();
  float* Os = (float*)&Ks[0][0];  // 4096 floats = 16 KiB, rows R=[0,64) x 64 d, XOR-swz
#pragma unroll
  for (int mf = 0; mf < 4; ++mf)
#pragma unroll
    for (int rg = 0; rg < 4; ++rg) {
      int d = 16 * mf + 4 * g + rg;
      int R0 = 32 * w + r15, R1 = 32 * w + 16 + r15;
      Os[R0 * 64 + (d ^ ((r15 & 7) << 3))] = ot0[mf][rg] * rl0;
      Os[R1 * 64 + (d ^ ((r15 & 7) << 3))] = ot1[mf][rg] * rl1;
    }
  __syncthreads();
  {
    int b = bh >> 4, h = bh & 15;
#pragma unroll
    for (int rep = 0; rep < 2; ++rep) {
      int idx = t + 128 * rep;
      int q = idx >> 2, c4 = idx & 3;
      float vals[16];
#pragma unroll
      for (int i = 0; i < 4; ++i) {
        f32x4 rd = *(const f32x4*)&Os[q * 64 + (((c4 * 16 + 4 * i) ^ ((q & 7) << 3)))];
        vals[4 * i + 0] = rd[0]; vals[4 * i + 1] = rd[1];
        vals[4 * i + 2] = rd[2]; vals[4 * i + 3] = rd[3];
      }
      union { uint32_t u[4]; s16x8 v; } o0, o1;
      o0.u[0] = cvtpk(vals[0], vals[1]);   o0.u[1] = cvtpk(vals[2], vals[3]);
      o0.u[2] = cvtpk(vals[4], vals[5]);   o0.u[3] = cvtpk(vals[6], vals[7]);
      o1.u[0] = cvtpk(vals[8], vals[9]);   o1.u[1] = cvtpk(vals[10], vals[11]);
      o1.u[2] = cvtpk(vals[12], vals[13]); o1.u[3] = cvtpk(vals[14], vals[15]);
      short* dst = Ao + ((size_t)b * kNT + q0 + q) * kDIM + h * kD + c4 * 16;
      *(s16x8*)dst = o0.v;
      *(s16x8*)(dst + 8) = o1.v;
    }
  }
}

extern "C" void kernel_launch(void* const* d_in, const int* in_sizes, int n_in,
                              void* d_out, int out_size, void* d_ws, size_t ws_size,
                              hipStream_t stream) {
  const float* x   = (const float*)d_in[0];
  const float* c   = (const float*)d_in[1];
  const float* wqx = (const float*)d_in[2];
  const float* bqx = (const float*)d_in[3];
  const float* wqc = (const float*)d_in[4];
  const float* bqc = (const float*)d_in[5];
  const float* sqx = (const float*)d_in[6];
  const float* skx = (const float*)d_in[7];
  const float* sqc = (const float*)d_in[8];
  const float* skc = (const float*)d_in[9];
  const float* wpx = (const float*)d_in[10];
  const float* bpx = (const float*)d_in[11];
  const float* wpc = (const float*)d_in[12];
  const float* bpc = (const float*)d_in[13];
  float* out = (float*)d_out;

  char* p = (char*)d_ws;
  short* xb   = (short*)p; p += (size_t)4096 * 1024 * 2;
  short* cb   = (short*)p; p += (size_t)512 * 1024 * 2;
  short* wqxt = (short*)p; p += (size_t)3072 * 1024 * 2;
  short* wqct = (short*)p; p += (size_t)3072 * 1024 * 2;
  short* wpxt = (short*)p; p += (size_t)1024 * 1024 * 2;
  short* wpct = (short*)p; p += (size_t)1024 * 1024 * 2;
  short* qb   = (short*)p; p += (size_t)32 * 2304 * 64 * 2;
  short* kb   = (short*)p; p += (size_t)32 * 2304 * 64 * 2;
  short* vtb  = (short*)p; p += (size_t)32 * 64 * 2304 * 2;
  short* ao   = (short*)p; p += (size_t)2 * 2304 * 1024 * 2;

  k_cast2<<<4608, 256, 0, stream>>>(x, xb, c, cb, 4096);
  k_tcast2<<<dim3(96, 32, 2), dim3(32, 8), 0, stream>>>(wqx, wqxt, wqc, wqct, 1024, 3072);
  k_tcast2<<<dim3(32, 32, 2), dim3(32, 8), 0, stream>>>(wpx, wpxt, wpc, wpct, 1024, 1024);

  // QKV projections (+bias, fused RMSNorm; q pre-scaled by 0.125*log2e)
  k_gemm<<<864, 256, 0, stream>>>(
      xb, wqxt, bqx, sqx, skx,
      cb, wqct, bqc, sqc, skc,
      qb, kb, vtb, nullptr, nullptr,
      11, 2048, 0, 0,
      8, 256, 0, 2048,
      32, 0, 24);

  k_attn<<<1152, 128, 0, stream>>>(qb, kb, vtb, ao);

  // output projections (f32 + bias) straight into d_out
  k_gemm<<<288, 256, 0, stream>>>(
      ao, wpxt, bpx, nullptr, nullptr,
      ao, wpct, bpc, nullptr, nullptr,
      nullptr, nullptr, nullptr, out, out + (size_t)4096 * 1024,
      11, 2304, 0, 0,
      8, 2304, 2048, 0,
      32, 1, 8);
}

// Round 6
// 129.399 us; speedup vs baseline: 3.4021x; 1.2174x over previous
//
#include <hip/hip_runtime.h>
#include <stdint.h>

typedef __attribute__((ext_vector_type(4))) float  f32x4;
typedef __attribute__((ext_vector_type(8))) short  s16x8;
typedef __attribute__((ext_vector_type(4))) short  s16x4;

constexpr int kDIM = 1024;
constexpr int kD   = 64;
constexpr int kNT  = 2304;   // Nx + Nc

static __device__ __forceinline__ short f2bf(float f) {
  union { float f; uint32_t i; } x; x.f = f;
  uint32_t r = x.i + 0x7fffu + ((x.i >> 16) & 1u);
  return (short)(r >> 16);
}
static __device__ __forceinline__ uint32_t cvtpk(float lo, float hi) {
  uint32_t r;
  asm volatile("v_cvt_pk_bf16_f32 %0, %1, %2" : "=v"(r) : "v"(lo), "v"(hi));
  return r;
}
// async global->LDS, 16B per lane; LDS dest = wave-uniform base + lane*16
static __device__ __forceinline__ void gll16(const short* g, short* l) {
  __builtin_amdgcn_global_load_lds((const __attribute__((address_space(1))) void*)g,
                                   (__attribute__((address_space(3))) void*)l, 16, 0, 0);
}
#define FENCE() asm volatile("" ::: "memory")
#define WAITV8() asm volatile("s_waitcnt vmcnt(8)" ::: "memory")
#define WAITV4() asm volatile("s_waitcnt vmcnt(4)" ::: "memory")
#define WAITV0() asm volatile("s_waitcnt vmcnt(0)" ::: "memory")

// ---------- cast f32 -> bf16 (x and c in one launch) ----------
__global__ __launch_bounds__(256) void k_cast2(const float* __restrict__ x,
                                               short* __restrict__ xb,
                                               const float* __restrict__ c,
                                               short* __restrict__ cb, int nxb) {
  int b = blockIdx.x;
  const float* in = x; short* out = xb;
  if (b >= nxb) { in = c; out = cb; b -= nxb; }
  int i = (b * 256 + threadIdx.x) * 4;
  f32x4 v = *(const f32x4*)(in + i);
  s16x4 o; o[0] = f2bf(v[0]); o[1] = f2bf(v[1]); o[2] = f2bf(v[2]); o[3] = f2bf(v[3]);
  *(s16x4*)(out + i) = o;
}

// ---------- transpose+cast: W[K][N] f32 -> Wt[N][K] bf16, two weights per launch ----------
__global__ __launch_bounds__(256) void k_tcast2(const float* __restrict__ W0,
                                                short* __restrict__ Wt0,
                                                const float* __restrict__ W1,
                                                short* __restrict__ Wt1,
                                                int K, int N) {
  const float* W = blockIdx.z ? W1 : W0;
  short* Wt = blockIdx.z ? Wt1 : Wt0;
  __shared__ float tile[32][33];
  int n0 = blockIdx.x * 32, k0 = blockIdx.y * 32;
  int tx = threadIdx.x, ty = threadIdx.y;
#pragma unroll
  for (int i2 = 0; i2 < 4; ++i2) {
    int r = ty + 8 * i2;
    tile[r][tx] = W[(size_t)(k0 + r) * N + n0 + tx];
  }
  __syncthreads();
#pragma unroll
  for (int i2 = 0; i2 < 4; ++i2) {
    int r = ty + 8 * i2;
    Wt[(size_t)(n0 + r) * K + k0 + tx] = f2bf(tile[tx][r]);
  }
}

// ---------- GEMM: C = A * Wt^T + bias, two param-sets per launch ----------
// Double-buffered LDS + counted vmcnt (no vmcnt(0) drain in steady state).
// 2-D XCD chunking: each XCD owns a (9 by) x (nx/2 bx) chunk of the block grid.
// epi==0: N=3072, fused RMSNorm on q/k heads (q gets extra 0.125*log2e), v transposed+permuted
// epi==1: N=1024, f32 rows to outp
__global__ __launch_bounds__(256, 2) void k_gemm(
    const short* A0, const short* Wt0, const float* bias0,
    const float* sq0, const float* sk0,
    const short* A1, const short* Wt1, const float* bias1,
    const float* sq1, const float* sk1,
    short* outq, short* outk, short* outvt,
    float* outp0, float* outp1,
    int rpbs0, int arstride0, int aoff0, int posoff0,
    int rpbs1, int arstride1, int aoff1, int posoff1,
    int ybreak, int epi, int nx) {
  __shared__ __align__(16) short As[2][8192];
  __shared__ __align__(16) short Bs[2][8192];
  const int t = threadIdx.x;
  const int lane = t & 63, w = t >> 6;
  const int g = lane >> 4, r15 = lane & 15;
  const int wm = w >> 1, wn = w & 1;

  // 2-D XCD chunk decode: xcd = lin&7 owns rows [(xcd&3)*9, +9) x cols [(xcd>>2)*(nx/2), +nx/2)
  int lin = blockIdx.x;
  int xcd = lin & 7, kk = lin >> 3;
  int by = (xcd & 3) * 9 + kk % 9;
  int bx = (xcd >> 2) * (nx >> 1) + kk / 9;

  const short* A; const short* Wt; const float* bias;
  const float* sq; const float* sk; float* outp;
  int rpbs, arstride, aoff, posoff, my;
  if (by < ybreak) {
    A = A0; Wt = Wt0; bias = bias0; sq = sq0; sk = sk0; outp = outp0;
    rpbs = rpbs0; arstride = arstride0; aoff = aoff0; posoff = posoff0; my = by;
  } else {
    A = A1; Wt = Wt1; bias = bias1; sq = sq1; sk = sk1; outp = outp1;
    rpbs = rpbs1; arstride = arstride1; aoff = aoff1; posoff = posoff1; my = by - ybreak;
  }
  const int m0 = my * 128, n0 = bx * 128;

  const short* aptr[4]; const short* bptr[4];
  int wofs[4];
#pragma unroll
  for (int it = 0; it < 4; ++it) {
    int slot = t + 256 * it;
    int row = slot >> 3, gp = slot & 7;
    int gl = gp ^ (row & 7);               // pre-swizzled source group
    int i = m0 + row;
    int arow = (i >> rpbs) * arstride + aoff + (i & ((1 << rpbs) - 1));
    aptr[it] = A + (size_t)arow * kDIM + 8 * gl;
    bptr[it] = Wt + (size_t)(n0 + row) * kDIM + 8 * gl;
    wofs[it] = (256 * it + 64 * w) * 8;    // wave-uniform LDS slot base (shorts)
  }

  f32x4 acc[4][4] = {};

  auto STAGE = [&](short* Asd, short* Bsd) {
#pragma unroll
    for (int it = 0; it < 4; ++it) {
      gll16(aptr[it], Asd + wofs[it]);
      gll16(bptr[it], Bsd + wofs[it]);
      aptr[it] += 64; bptr[it] += 64;
    }
  };

  auto kstep = [&](const short* Ab, const short* Bb, short* Asd, short* Bsd,
                   bool last, bool pref) {
    if (last) WAITV0(); else WAITV8();      // tile's 8 loads landed (per-wave)
    __builtin_amdgcn_s_barrier();           // all waves' loads landed
    FENCE();
#pragma unroll
    for (int ks = 0; ks < 2; ++ks) {
      s16x8 af[4], bfr[4];
#pragma unroll
      for (int mf = 0; mf < 4; ++mf) {
        int row = wm * 64 + mf * 16 + r15;
        af[mf] = *(const s16x8*)(Ab + row * 64 + (((g + 4 * ks) ^ (row & 7)) * 8));
      }
#pragma unroll
      for (int nf = 0; nf < 4; ++nf) {
        int row = wn * 64 + nf * 16 + r15;
        bfr[nf] = *(const s16x8*)(Bb + row * 64 + (((g + 4 * ks) ^ (row & 7)) * 8));
      }
#pragma unroll
      for (int mf = 0; mf < 4; ++mf)
#pragma unroll
        for (int nf = 0; nf < 4; ++nf)
          acc[mf][nf] = __builtin_amdgcn_mfma_f32_16x16x32_bf16(af[mf], bfr[nf], acc[mf][nf], 0, 0, 0);
    }
    FENCE();
    __builtin_amdgcn_s_barrier();           // all waves done reading this buffer
    FENCE();
    if (pref) STAGE(Asd, Bsd);              // restage freed buffer (tile t+2)
  };

  // prologue: tiles 0,1 in flight (16 outstanding per wave)
  STAGE(&As[0][0], &Bs[0][0]);
  STAGE(&As[1][0], &Bs[1][0]);
  for (int pp = 0; pp < 8; ++pp) {
    kstep(&As[0][0], &Bs[0][0], &As[0][0], &Bs[0][0], false,   pp < 7);
    kstep(&As[1][0], &Bs[1][0], &As[1][0], &Bs[1][0], pp == 7, pp < 7);
  }

  const int rpbm = (1 << rpbs) - 1;
  if (epi == 1) {
#pragma unroll
    for (int mf = 0; mf < 4; ++mf)
#pragma unroll
      for (int nf = 0; nf < 4; ++nf) {
        int i = m0 + wm * 64 + mf * 16 + 4 * g;
        int j = n0 + wn * 64 + nf * 16 + r15;
        f32x4 v = acc[mf][nf];
        float bj = bias[j];
#pragma unroll
        for (int rg = 0; rg < 4; ++rg)
          outp[(size_t)(i + rg) * 1024 + j] = v[rg] + bj;
      }
    return;
  }
  const int eblk = (n0 + wn * 64) >> 10;   // wave-uniform: 0=q, 1=k, 2=v
  const int hh = ((n0 + wn * 64) >> 6) & 15;
  if (eblk == 2) {
#pragma unroll
    for (int mf = 0; mf < 4; ++mf)
#pragma unroll
      for (int nf = 0; nf < 4; ++nf) {
        int i = m0 + wm * 64 + mf * 16 + 4 * g;
        int j = n0 + wn * 64 + nf * 16 + r15;
        f32x4 v = acc[mf][nf];
        float bj = bias[j];
        int d = j & 63;
        int b = i >> rpbs;
        int pos = (i & rpbm) + posoff;
        // permuted column order within each 64-block (keeps low 2 bits):
        int pg = (pos & ~63) | (pos & 32) | (((pos >> 2) & 3) << 3) |
                 (((pos >> 4) & 1) << 2) | (pos & 3);
        size_t base = ((size_t)((b * 16 + hh) * 64 + d)) * kNT + pg;
        s16x4 o;
        o[0] = f2bf(v[0] + bj); o[1] = f2bf(v[1] + bj);
        o[2] = f2bf(v[2] + bj); o[3] = f2bf(v[3] + bj);
        *(s16x4*)(outvt + base) = o;
      }
  } else {
    const float* sv = (eblk == 0) ? sq : sk;
    short* dstb = (eblk == 0) ? outq : outk;
    // fold attention scale*log2(e) into q (softmax becomes raw exp2)
    const float post = (eblk == 0) ? 0.125f * 1.44269504f : 1.0f;
    float sl[4], bj4[4];
#pragma unroll
    for (int nf = 0; nf < 4; ++nf) {
      bj4[nf] = bias[n0 + wn * 64 + nf * 16 + r15];
      sl[nf] = sv[nf * 16 + r15] * post;
    }
#pragma unroll
    for (int mf = 0; mf < 4; ++mf) {
      float vb[4][4];
#pragma unroll
      for (int nf = 0; nf < 4; ++nf)
#pragma unroll
        for (int rg = 0; rg < 4; ++rg)
          vb[nf][rg] = acc[mf][nf][rg] + bj4[nf];
#pragma unroll
      for (int rg = 0; rg < 4; ++rg) {
        float ss = vb[0][rg] * vb[0][rg];
        ss = __builtin_fmaf(vb[1][rg], vb[1][rg], ss);
        ss = __builtin_fmaf(vb[2][rg], vb[2][rg], ss);
        ss = __builtin_fmaf(vb[3][rg], vb[3][rg], ss);
        ss += __shfl_xor(ss, 1); ss += __shfl_xor(ss, 2);
        ss += __shfl_xor(ss, 4); ss += __shfl_xor(ss, 8);
        float f = rsqrtf(ss * (1.f / 64.f) + 1e-6f);
        int i = m0 + wm * 64 + mf * 16 + 4 * g + rg;
        int b = i >> rpbs;
        int pos = (i & rpbm) + posoff;
        short* dst = dstb + ((size_t)((b * 16 + hh) * kNT + pos)) * 64;
#pragma unroll
        for (int nf = 0; nf < 4; ++nf)
          dst[nf * 16 + r15] = f2bf(vb[nf][rg] * f * sl[nf]);
      }
    }
  }
}

// ---------- Flash attention: 4 waves x 32 q (QBLK=128), shared KV (dbuf, KVBLK=64) ----------
// No-max softmax (RMSNorm bounds |score*log2e| <= 11.6): p = exp2(S^T).
// Counted-vmcnt pipeline; l accumulated via ones-MFMA (no cross-lane reduce at all).
// XCD-aware head placement: each head's 18 q-blocks land on one XCD.
__global__ __launch_bounds__(256, 3) void k_attn(
    const short* __restrict__ Q, const short* __restrict__ K,
    const short* __restrict__ Vt, short* __restrict__ Ao) {
  __shared__ __align__(16) short S[16384];  // 32 KB: K dbuf [0,8192), V dbuf [8192,16384)
  const int t = threadIdx.x;
  const int lane = t & 63, w = t >> 6;
  const int g = lane >> 4, r15 = lane & 15;
  // head/qblock decode: lin&7 = XCD; 4 heads per XCD, 18 q-blocks (of 128) per head
  const int lin = blockIdx.x;
  const int idx = lin >> 3;
  const int bh = (lin & 7) * 4 + idx / 18;
  const int q0 = (idx % 18) * 128;

  // Q B-fragments, 2 per wave (q = q0 + 32w + 16qi + r15); elem j -> d = 8g+j+32a
  s16x8 qf[2][2];
#pragma unroll
  for (int qi = 0; qi < 2; ++qi) {
    const short* qrow = Q + ((size_t)bh * kNT + q0 + 32 * w + 16 * qi + r15) * kD;
    qf[qi][0] = *(const s16x8*)(qrow + 8 * g);
    qf[qi][1] = *(const s16x8*)(qrow + 32 + 8 * g);
  }

  // staging: 512 16B-slots per matrix per tile, 2 per thread (4 gll/wave/tile)
  const short* kptr[2]; const short* vptr[2];
  int sb[2];
#pragma unroll
  for (int it = 0; it < 2; ++it) {
    int slot = t + 256 * it;
    int row = slot >> 3, gp = slot & 7;
    int gl = gp ^ (row & 7);
    kptr[it] = K + ((size_t)bh * kNT + row) * kD + 8 * gl;
    vptr[it] = Vt + ((size_t)bh * kD + row) * kNT + 8 * gl;
    sb[it] = (256 * it + 64 * w) * 8;
  }

  // hoisted LDS read offsets (element units)
  int ko[2][4], vo[2][4];
#pragma unroll
  for (int a = 0; a < 2; ++a)
#pragma unroll
    for (int rf = 0; rf < 4; ++rf) {
      int row = 16 * rf + r15;
      ko[a][rf] = row * 64 + (((g + 4 * a) ^ (row & 7)) * 8);
      vo[a][rf] = row * 64 + (((4 * a + g) ^ (row & 7)) * 8);
    }

  // all-ones bf16 A-fragment for the l-sum MFMA
  s16x8 onesf;
#pragma unroll
  for (int j = 0; j < 8; ++j) onesf[j] = (short)0x3F80;

  f32x4 ot0[4] = {}, ot1[4] = {};
  f32x4 ls0 = {}, ls1 = {};   // every element = l[q] at the end
  short* Kb0 = S;          short* Kb1 = S + 4096;
  short* Vb0 = S + 8192;   short* Vb1 = S + 12288;

  auto STAGE = [&](short* kst, short* vst) {
#pragma unroll
    for (int it = 0; it < 2; ++it) {
      gll16(kptr[it], kst + sb[it]);
      kptr[it] += 64 * kD;
    }
#pragma unroll
    for (int it = 0; it < 2; ++it) {
      gll16(vptr[it], vst + sb[it]);
      vptr[it] += 64;
    }
  };

  auto tile = [&](const short* Kb, const short* Vb, short* kst, short* vst,
                  bool last, bool pref) {
    if (last) WAITV0(); else WAITV4();   // this tile's 4 loads landed (per-wave)
    __builtin_amdgcn_s_barrier();
    FENCE();
    // S^T = K * Q^T for both q-frags (K frags shared)
    f32x4 st0[4] = {}, st1[4] = {};
    __builtin_amdgcn_s_setprio(1);
#pragma unroll
    for (int a = 0; a < 2; ++a) {
#pragma unroll
      for (int rf = 0; rf < 4; ++rf) {
        s16x8 kf = *(const s16x8*)(Kb + ko[a][rf]);
        st0[rf] = __builtin_amdgcn_mfma_f32_16x16x32_bf16(kf, qf[0][a], st0[rf], 0, 0, 0);
        st1[rf] = __builtin_amdgcn_mfma_f32_16x16x32_bf16(kf, qf[1][a], st1[rf], 0, 0, 0);
      }
    }
    __builtin_amdgcn_s_setprio(0);
    // softmax: pure exp2 (scale folded into q); no l adds (ones-MFMA below)
    float pv0[4][4], pv1[4][4];
#pragma unroll
    for (int rf = 0; rf < 4; ++rf)
#pragma unroll
      for (int j = 0; j < 4; ++j) {
        pv0[rf][j] = __builtin_amdgcn_exp2f(st0[rf][j]);
        pv1[rf][j] = __builtin_amdgcn_exp2f(st1[rf][j]);
      }
    // P^T pack: element j <-> kv = 32c + 4g + (j&3) + 16*(j>>2)
    s16x8 pf0[2], pf1[2];
#pragma unroll
    for (int c = 0; c < 2; ++c) {
      union { uint32_t u[4]; s16x8 v; } a, b;
      a.u[0] = cvtpk(pv0[2 * c][0], pv0[2 * c][1]);
      a.u[1] = cvtpk(pv0[2 * c][2], pv0[2 * c][3]);
      a.u[2] = cvtpk(pv0[2 * c + 1][0], pv0[2 * c + 1][1]);
      a.u[3] = cvtpk(pv0[2 * c + 1][2], pv0[2 * c + 1][3]);
      pf0[c] = a.v;
      b.u[0] = cvtpk(pv1[2 * c][0], pv1[2 * c][1]);
      b.u[1] = cvtpk(pv1[2 * c][2], pv1[2 * c][3]);
      b.u[2] = cvtpk(pv1[2 * c + 1][0], pv1[2 * c + 1][1]);
      b.u[3] = cvtpk(pv1[2 * c + 1][2], pv1[2 * c + 1][3]);
      pf1[c] = b.v;
    }
    // O^T += V^T * P^T (V frags shared by both q-frags); l-sum via ones-MFMA
    __builtin_amdgcn_s_setprio(1);
#pragma unroll
    for (int mf = 0; mf < 4; ++mf)
#pragma unroll
      for (int c = 0; c < 2; ++c) {
        s16x8 vf = *(const s16x8*)(Vb + vo[c][mf]);
        ot0[mf] = __builtin_amdgcn_mfma_f32_16x16x32_bf16(vf, pf0[c], ot0[mf], 0, 0, 0);
        ot1[mf] = __builtin_amdgcn_mfma_f32_16x16x32_bf16(vf, pf1[c], ot1[mf], 0, 0, 0);
      }
#pragma unroll
    for (int c = 0; c < 2; ++c) {
      ls0 = __builtin_amdgcn_mfma_f32_16x16x32_bf16(onesf, pf0[c], ls0, 0, 0, 0);
      ls1 = __builtin_amdgcn_mfma_f32_16x16x32_bf16(onesf, pf1[c], ls1, 0, 0, 0);
    }
    __builtin_amdgcn_s_setprio(0);
    FENCE();
    __builtin_amdgcn_s_barrier();        // all waves done reading this buffer
    FENCE();
    if (pref) STAGE(kst, vst);           // restage freed buffer (tile t+2)
  };

  // prologue: tiles 0,1 in flight
  STAGE(Kb0, Vb0);
  STAGE(Kb1, Vb1);
  for (int pp = 0; pp < 18; ++pp) {
    tile(Kb0, Vb0, Kb0, Vb0, false,    pp < 17);
    tile(Kb1, Vb1, Kb1, Vb1, pp == 17, pp < 17);
  }

  float rl0 = 1.f / ls0[0], rl1 = 1.f / ls1[0];

  // epilogue: transpose O^T -> O via LDS (reuse S as f32 [128 q][64 d]), coalesced store
  __syncthreads();
  float* Os = (float*)S;   // 8192 floats = 32 KB
#pragma unroll
  for (int mf = 0; mf < 4; ++mf)
#pragma unroll
    for (int rg = 0; rg < 4; ++rg) {
      int d = 16 * mf + 4 * g + rg;
      int R0 = 32 * w + r15, R1 = 32 * w + 16 + r15;
      Os[R0 * 64 + (d ^ ((r15 & 7) << 3))] = ot0[mf][rg] * rl0;
      Os[R1 * 64 + (d ^ ((r15 & 7) << 3))] = ot1[mf][rg] * rl1;
    }
  __syncthreads();
  {
    int b = bh >> 4, h = bh & 15;
#pragma unroll
    for (int rep = 0; rep < 2; ++rep) {
      int idx = t + 256 * rep;
      int q = idx >> 2, c4 = idx & 3;
      float vals[16];
#pragma unroll
      for (int i = 0; i < 4; ++i) {
        f32x4 rd = *(const f32x4*)&Os[q * 64 + (((c4 * 16 + 4 * i) ^ ((q & 7) << 3)))];
        vals[4 * i + 0] = rd[0]; vals[4 * i + 1] = rd[1];
        vals[4 * i + 2] = rd[2]; vals[4 * i + 3] = rd[3];
      }
      union { uint32_t u[4]; s16x8 v; } o0, o1;
      o0.u[0] = cvtpk(vals[0], vals[1]);   o0.u[1] = cvtpk(vals[2], vals[3]);
      o0.u[2] = cvtpk(vals[4], vals[5]);   o0.u[3] = cvtpk(vals[6], vals[7]);
      o1.u[0] = cvtpk(vals[8], vals[9]);   o1.u[1] = cvtpk(vals[10], vals[11]);
      o1.u[2] = cvtpk(vals[12], vals[13]); o1.u[3] = cvtpk(vals[14], vals[15]);
      short* dst = Ao + ((size_t)b * kNT + q0 + q) * kDIM + h * kD + c4 * 16;
      *(s16x8*)dst = o0.v;
      *(s16x8*)(dst + 8) = o1.v;
    }
  }
}

extern "C" void kernel_launch(void* const* d_in, const int* in_sizes, int n_in,
                              void* d_out, int out_size, void* d_ws, size_t ws_size,
                              hipStream_t stream) {
  const float* x   = (const float*)d_in[0];
  const float* c   = (const float*)d_in[1];
  const float* wqx = (const float*)d_in[2];
  const float* bqx = (const float*)d_in[3];
  const float* wqc = (const float*)d_in[4];
  const float* bqc = (const float*)d_in[5];
  const float* sqx = (const float*)d_in[6];
  const float* skx = (const float*)d_in[7];
  const float* sqc = (const float*)d_in[8];
  const float* skc = (const float*)d_in[9];
  const float* wpx = (const float*)d_in[10];
  const float* bpx = (const float*)d_in[11];
  const float* wpc = (const float*)d_in[12];
  const float* bpc = (const float*)d_in[13];
  float* out = (float*)d_out;

  char* p = (char*)d_ws;
  short* xb   = (short*)p; p += (size_t)4096 * 1024 * 2;
  short* cb   = (short*)p; p += (size_t)512 * 1024 * 2;
  short* wqxt = (short*)p; p += (size_t)3072 * 1024 * 2;
  short* wqct = (short*)p; p += (size_t)3072 * 1024 * 2;
  short* wpxt = (short*)p; p += (size_t)1024 * 1024 * 2;
  short* wpct = (short*)p; p += (size_t)1024 * 1024 * 2;
  short* qb   = (short*)p; p += (size_t)32 * 2304 * 64 * 2;
  short* kb   = (short*)p; p += (size_t)32 * 2304 * 64 * 2;
  short* vtb  = (short*)p; p += (size_t)32 * 64 * 2304 * 2;
  short* ao   = (short*)p; p += (size_t)2 * 2304 * 1024 * 2;

  k_cast2<<<4608, 256, 0, stream>>>(x, xb, c, cb, 4096);
  k_tcast2<<<dim3(96, 32, 2), dim3(32, 8), 0, stream>>>(wqx, wqxt, wqc, wqct, 1024, 3072);
  k_tcast2<<<dim3(32, 32, 2), dim3(32, 8), 0, stream>>>(wpx, wpxt, wpc, wpct, 1024, 1024);

  // QKV projections (+bias, fused RMSNorm; q pre-scaled by 0.125*log2e)
  k_gemm<<<864, 256, 0, stream>>>(
      xb, wqxt, bqx, sqx, skx,
      cb, wqct, bqc, sqc, skc,
      qb, kb, vtb, nullptr, nullptr,
      11, 2048, 0, 0,
      8, 256, 0, 2048,
      32, 0, 24);

  k_attn<<<576, 256, 0, stream>>>(qb, kb, vtb, ao);

  // output projections (f32 + bias) straight into d_out
  k_gemm<<<288, 256, 0, stream>>>(
      ao, wpxt, bpx, nullptr, nullptr,
      ao, wpct, bpc, nullptr, nullptr,
      nullptr, nullptr, nullptr, out, out + (size_t)4096 * 1024,
      11, 2304, 0, 0,
      8, 2304, 2048, 0,
      32, 1, 8);
}